// Round 11
// baseline (764.812 us; speedup 1.0000x reference)
//
#include <hip/hip_runtime.h>

typedef unsigned short ushort_t;
typedef __attribute__((ext_vector_type(8))) short short8;   // 8 bf16 (4 VGPRs)
typedef __attribute__((ext_vector_type(4))) float f32x4;

#define S_  2048
#define Dm  2048
#define NH  16
#define NKV 4
#define HD_ 128
// SCALE * log2(e): exp(s*SCALE) == exp2(s*C2)
#define C2_ 0.12751879524465536f

__device__ __forceinline__ ushort_t f2bf(float f) {
  union { float f; unsigned u; } v; v.f = f;
  unsigned u = v.u;
  return (ushort_t)((u + 0x7FFFu + ((u >> 16) & 1u)) >> 16);   // RNE
}
__device__ __forceinline__ ushort_t f2bf2(float f) {            // round-half-up (2 VALU ops)
  union { float f; unsigned u; } v; v.f = f;
  return (ushort_t)((v.u + 0x8000u) >> 16);
}
__device__ __forceinline__ float bf2f(ushort_t h) {
  union { unsigned u; float f; } v; v.u = ((unsigned)h) << 16;
  return v.f;
}
__device__ __forceinline__ void gl_lds16(const void* g, void* l) {
  __builtin_amdgcn_global_load_lds((const __attribute__((address_space(1))) void*)g,
                                   (__attribute__((address_space(3))) void*)l, 16, 0, 0);
}

// ------- merged prep: bf16 convert (<8192) + 4 weight transposes + sync-flag zero -------
__global__ void prep_k(const float* __restrict__ hs, ushort_t* __restrict__ hsb,
                       const float* __restrict__ Wq, const float* __restrict__ Wk,
                       const float* __restrict__ Wv, const float* __restrict__ Wo,
                       ushort_t* __restrict__ wtqkv, ushort_t* __restrict__ wto,
                       int* __restrict__ syncp) {
  __shared__ float tile[32][33];
  const int id = blockIdx.x;
  if (id >= 24576) {   // zero the 1057-int sync region (ticket + 1024 linv flags + 32 mt flags)
    for (int i = threadIdx.x; i < 1057; i += 256) syncp[i] = 0;
    return;
  }
  if (id < 8192) {
    int i = id * 256 + threadIdx.x;
    float4 v = ((const float4*)hs)[i];
    union { ushort_t u[4]; uint2 v2; } o;
    o.u[0] = f2bf(v.x); o.u[1] = f2bf(v.y); o.u[2] = f2bf(v.z); o.u[3] = f2bf(v.w);
    *(uint2*)&hsb[(size_t)i * 4] = o.v2;
    return;
  }
  const int id2 = id - 8192;
  const int z = id2 >> 12, ky = (id2 >> 6) & 63, nx = id2 & 63;
  const float* src;
  ushort_t* dst;
  int N;
  switch (z) {
    case 0: src = Wq; dst = wtqkv; N = 2048; break;
    case 1: src = Wk; dst = wtqkv + (size_t)2048 * 2048; N = 512; break;
    case 2: src = Wv; dst = wtqkv + (size_t)2560 * 2048; N = 512; break;
    default: src = Wo; dst = wto; N = 2048; break;
  }
  int n0 = nx * 32, k0 = ky * 32;
  if (n0 >= N) return;
  int c = threadIdx.x & 31, r = threadIdx.x >> 5;   // r: 0..7
#pragma unroll
  for (int i = 0; i < 32; i += 8)
    tile[r + i][c] = src[(size_t)(k0 + r + i) * N + n0 + c];
  __syncthreads();
#pragma unroll
  for (int i = 0; i < 32; i += 8)
    dst[(size_t)(n0 + r + i) * 2048 + k0 + c] = f2bf(tile[c][r + i]);
}

// ---------------- GEMM QKV (dbuf, XCD swizzle) + bias + fused RoPE + fused V-transpose ----------
__global__ __launch_bounds__(256, 2) void gemm_qkv_k(
    const ushort_t* __restrict__ A, const ushort_t* __restrict__ Bt, ushort_t* __restrict__ C,
    const float* __restrict__ bq, const float* __restrict__ bk2, const float* __restrict__ bv,
    const float* __restrict__ cosT, const float* __restrict__ sinT, ushort_t* __restrict__ vt) {
  const int N = 3072, K = 2048;
  __shared__ ushort_t smem[16384];   // 32 KB: staging dbuf; later transpose tile / rope fbuf
  ushort_t* lA0 = smem;              // [2][4096], source-pre-swizzled: slot ^= (row>>1)&3
  ushort_t* lB0 = smem + 8192;
  const int lin = blockIdx.x;                    // 768 blocks
  const int nid = (lin & 7) * 96 + (lin >> 3);   // XCD-chunked swizzle (768%8==0)
  const int n0 = (nid % 24) * 128, m0 = (nid / 24) * 128;
  const int t = threadIdx.x;
  const int w = t >> 6, l = t & 63, lr = l & 15, lg = l >> 4;
  const int wr = w >> 1, wc = w & 1;
  const int srow = t >> 2, ssl = t & 3;

  auto stage = [&](int kt, int bufi) {
    int r0 = srow, r1 = srow + 64;
    gl_lds16(A + (size_t)(m0 + r0) * K + kt + ((ssl ^ ((r0 >> 1) & 3)) << 3),
             &lA0[bufi * 4096 + w * 512]);
    gl_lds16(A + (size_t)(m0 + r1) * K + kt + ((ssl ^ ((r1 >> 1) & 3)) << 3),
             &lA0[bufi * 4096 + 2048 + w * 512]);
    gl_lds16(Bt + (size_t)(n0 + r0) * K + kt + ((ssl ^ ((r0 >> 1) & 3)) << 3),
             &lB0[bufi * 4096 + w * 512]);
    gl_lds16(Bt + (size_t)(n0 + r1) * K + kt + ((ssl ^ ((r1 >> 1) & 3)) << 3),
             &lB0[bufi * 4096 + 2048 + w * 512]);
  };

  f32x4 acc[4][4];
#pragma unroll
  for (int i = 0; i < 4; i++)
#pragma unroll
    for (int j = 0; j < 4; j++) acc[i][j] = (f32x4){0.f, 0.f, 0.f, 0.f};

  stage(0, 0);
  const int nit = K / 32;   // 64
  for (int it = 0; it < nit; it++) {
    const int cur = it & 1;
    if (it + 1 < nit) {
      stage((it + 1) * 32, cur ^ 1);
      asm volatile("s_waitcnt vmcnt(4)" ::: "memory");   // current tile's 4 loads done
    } else {
      asm volatile("s_waitcnt vmcnt(0)" ::: "memory");
    }
    __builtin_amdgcn_s_barrier();
    short8 af[4], bfr[4];
#pragma unroll
    for (int mi = 0; mi < 4; mi++) {
      int row = wr * 64 + mi * 16 + lr;
      af[mi] = *(const short8*)((const char*)(lA0 + cur * 4096) + row * 64 +
                                ((lg ^ ((row >> 1) & 3)) << 4));
    }
#pragma unroll
    for (int ni = 0; ni < 4; ni++) {
      int row = wc * 64 + ni * 16 + lr;
      bfr[ni] = *(const short8*)((const char*)(lB0 + cur * 4096) + row * 64 +
                                 ((lg ^ ((row >> 1) & 3)) << 4));
    }
#pragma unroll
    for (int mi = 0; mi < 4; mi++)
#pragma unroll
      for (int ni = 0; ni < 4; ni++)
        acc[mi][ni] = __builtin_amdgcn_mfma_f32_16x16x32_bf16(af[mi], bfr[ni], acc[mi][ni], 0, 0, 0);
    __builtin_amdgcn_s_barrier();   // all waves done reading buf[cur] before restage
  }

  // epilogue: bias; RoPE (Q/K blocks) via partner-wave LDS exchange; V blocks also fill
  // the LDS transpose tile for the fused vt write.
  const bool isV = (n0 >= 2560);
  float* fbuf = (float*)smem;        // 16 KB, staging done
  const int pw_ = w ^ 1;             // partner wave: same wr, wc^1
#pragma unroll
  for (int mi = 0; mi < 4; mi++) {
    float vv[4][4];
#pragma unroll
    for (int ni = 0; ni < 4; ni++)
#pragma unroll
      for (int r = 0; r < 4; r++) {
        int col = n0 + wc * 64 + ni * 16 + lr;
        float bias = (col < 2048) ? bq[col] : (col < 2560) ? bk2[col - 2048] : bv[col - 2560];
        vv[ni][r] = acc[mi][ni][r] + bias;
      }
    if (!isV) {
      __syncthreads();
#pragma unroll
      for (int ni = 0; ni < 4; ni++)
#pragma unroll
        for (int r = 0; r < 4; r++)
          fbuf[w * 1024 + (lg * 4 + r) * 64 + ni * 16 + lr] = vv[ni][r];
      __syncthreads();
#pragma unroll
      for (int ni = 0; ni < 4; ni++)
#pragma unroll
        for (int r = 0; r < 4; r++) {
          float pv = fbuf[pw_ * 1024 + (lg * 4 + r) * 64 + ni * 16 + lr];
          int row = m0 + wr * 64 + mi * 16 + lg * 4 + r;   // = b*2048+s
          int d = wc * 64 + ni * 16 + lr;                  // 0..127 within head
          float c = cosT[(size_t)row * HD_ + d];
          float sn = sinT[(size_t)row * HD_ + d];
          vv[ni][r] = (wc == 0) ? vv[ni][r] * c - pv * sn : vv[ni][r] * c + pv * sn;
        }
    }
#pragma unroll
    for (int ni = 0; ni < 4; ni++)
#pragma unroll
      for (int r = 0; r < 4; r++) {
        int row = m0 + wr * 64 + mi * 16 + lg * 4 + r;
        int col = n0 + wc * 64 + ni * 16 + lr;
        ushort_t hv = f2bf(vv[ni][r]);
        C[(size_t)row * N + col] = hv;
        if (isV) {
          int colL = wc * 64 + ni * 16 + lr;            // d within head
          int rowL = wr * 64 + mi * 16 + lg * 4 + r;    // s within tile
          smem[colL * 128 + (rowL ^ ((colL & 7) << 4))] = hv;
        }
      }
  }
  if (isV) {
    __syncthreads();
    const int kvh = (n0 - 2560) >> 7;
    const int b = m0 >> 11, s0v = m0 & 2047;
    const size_t vbase = (size_t)(b * 4 + kvh) * 128;
#pragma unroll
    for (int j = 0; j < 8; j++) {
      int cid = j * 256 + t;
      int d = cid >> 4, sc = cid & 15;
      int rowStart = (sc * 8) ^ ((d & 7) << 4);
      short8 v8 = *(const short8*)&smem[d * 128 + rowStart];
      *(short8*)&vt[(vbase + d) * S_ + s0v + sc * 8] = v8;
    }
  }
}

// ---------------- fused attn + tail, ticket-scheduled producer/consumer ----------------
// tickets [0,1024):   attention for (bh, qt), heavy-qt first  -> linv, attnO, outW zero-fill
// tickets [1024,2048): attn_weights recompute+normalize (bh, qt), flag-gated on linv
// tickets [2048,2560): Wo projection GEMM m-tile, flag-gated on 32 attnO producers
__global__ __launch_bounds__(256, 2) void fused_k(
    const ushort_t* __restrict__ qkv, const ushort_t* __restrict__ vt,
    float* __restrict__ linv_g, ushort_t* __restrict__ attnO, float* __restrict__ outW,
    const ushort_t* __restrict__ wto, float* __restrict__ outO, int* __restrict__ sync) {
  __shared__ ushort_t smem[36864];   // 72 KB, role-dependent aliasing
  __shared__ int s_tk;
  const int t = threadIdx.x;
  if (t == 0)
    s_tk = __hip_atomic_fetch_add(&sync[0], 1, __ATOMIC_RELAXED, __HIP_MEMORY_SCOPE_AGENT);
  __syncthreads();
  const int bx = s_tk;
  int* flin = sync + 1;      // 1024: per-(bh,qt) linv/attnO ready
  int* fmt = sync + 1025;    // 32: per-m-tile attnO contribution count (target 32)
  const int w = t >> 6, l = t & 63, lr = l & 15, lg = l >> 4;

  if (bx < 1024) {
    // ======== attention producer (single q-tile) ========
    ushort_t* lK = smem;                       // [2][8192] ush: [k][d], slot ^= row&15
    ushort_t* lV = smem + 16384;               // [2][8192] ush: [d][k], slot ^= row&7
    ushort_t* lPw = smem + 32768 + w * 1024;   // per-wave P~ 16x64, slot ^= row&7
    const int qt = 31 - (bx >> 5);             // heavy first for LPT packing
    const int bh = bx & 31;
    const int b = bh >> 4, h = bh & 15, kvh = h >> 2;
    const int qw = qt * 64 + w * 16;
    const int nkt = qt + 1;

    auto stage = [&](int kt, int bufi) {
#pragma unroll
      for (int c = 0; c < 4; c++) {
        int row = c * 16 + (t >> 4), sl = t & 15;
        gl_lds16(qkv + (size_t)(b * S_ + kt * 64 + row) * 3072 + 2048 + kvh * HD_ +
                     ((sl ^ (row & 15)) << 3),
                 &lK[bufi * 8192 + c * 2048 + w * 512]);
      }
#pragma unroll
      for (int c = 0; c < 4; c++) {
        int row = c * 32 + (t >> 3), sl = t & 7;
        gl_lds16(vt + (size_t)((b * 4 + kvh) * 128 + row) * S_ + kt * 64 +
                     ((sl ^ (row & 7)) << 3),
                 &lV[bufi * 8192 + c * 2048 + w * 512]);
      }
    };

    short8 qf[4];
#pragma unroll
    for (int kc = 0; kc < 4; kc++)
      qf[kc] = *(const short8*)&qkv[(size_t)(b * S_ + qw + lr) * 3072 + h * HD_ + kc * 32 + lg * 8];

    float lsum[4];
    f32x4 o[8];
#pragma unroll
    for (int r = 0; r < 4; r++) lsum[r] = 0.f;
#pragma unroll
    for (int dj = 0; dj < 8; dj++) o[dj] = (f32x4){0.f, 0.f, 0.f, 0.f};

    stage(0, 0);
    for (int kt = 0; kt < nkt; kt++) {
      const int cur = kt & 1;
      if (kt + 1 < nkt) {
        stage(kt + 1, cur ^ 1);
        asm volatile("s_waitcnt vmcnt(8)" ::: "memory");
      } else {
        asm volatile("s_waitcnt vmcnt(0)" ::: "memory");
      }
      __builtin_amdgcn_s_barrier();

      f32x4 s[4];
#pragma unroll
      for (int ni = 0; ni < 4; ni++) s[ni] = (f32x4){0.f, 0.f, 0.f, 0.f};
      __builtin_amdgcn_s_setprio(1);
#pragma unroll
      for (int kc = 0; kc < 4; kc++) {
        short8 kf[4];
#pragma unroll
        for (int ni = 0; ni < 4; ni++) {
          int row = ni * 16 + lr;
          kf[ni] = *(const short8*)((const char*)(lK + cur * 8192) + row * 256 +
                                    (((kc * 4 + lg) ^ (row & 15)) << 4));
        }
#pragma unroll
        for (int ni = 0; ni < 4; ni++)
          s[ni] = __builtin_amdgcn_mfma_f32_16x16x32_bf16(qf[kc], kf[ni], s[ni], 0, 0, 0);
      }
      __builtin_amdgcn_s_setprio(0);

      if (kt == nkt - 1) {
#pragma unroll
        for (int ni = 0; ni < 4; ni++)
#pragma unroll
          for (int r = 0; r < 4; r++) {
            float p = exp2f(s[ni][r] * C2_);
            int colg = kt * 64 + ni * 16 + lr;
            int rowg = qw + lg * 4 + r;
            if (colg > rowg) p = 0.f;
            lsum[r] += p;
            int rowl = lg * 4 + r, col = ni * 16 + lr;
            lPw[rowl * 64 + (((col >> 3) ^ (rowl & 7)) << 3) + (col & 7)] = f2bf2(p);
          }
      } else {
#pragma unroll
        for (int ni = 0; ni < 4; ni++)
#pragma unroll
          for (int r = 0; r < 4; r++) {
            float p = exp2f(s[ni][r] * C2_);
            lsum[r] += p;
            int rowl = lg * 4 + r, col = ni * 16 + lr;
            lPw[rowl * 64 + (((col >> 3) ^ (rowl & 7)) << 3) + (col & 7)] = f2bf2(p);
          }
      }

      __builtin_amdgcn_s_setprio(1);
#pragma unroll
      for (int kc = 0; kc < 2; kc++) {
        short8 pa;
        {
          int row = lr;
          pa = *(const short8*)((const char*)lPw + row * 128 + (((kc * 4 + lg) ^ (row & 7)) << 4));
        }
#pragma unroll
        for (int dj = 0; dj < 8; dj++) {
          int row = dj * 16 + lr;
          short8 vb = *(const short8*)((const char*)(lV + cur * 8192) + row * 128 +
                                       (((kc * 4 + lg) ^ (row & 7)) << 4));
          o[dj] = __builtin_amdgcn_mfma_f32_16x16x32_bf16(pa, vb, o[dj], 0, 0, 0);
        }
      }
      __builtin_amdgcn_s_setprio(0);
      __builtin_amdgcn_s_barrier();
    }

    float inv_l[4];
#pragma unroll
    for (int r = 0; r < 4; r++) {
      float sum = lsum[r];
#pragma unroll
      for (int off = 1; off < 16; off <<= 1) sum += __shfl_xor(sum, off);
      inv_l[r] = 1.f / sum;
      if (lr == 0) linv_g[(size_t)bh * S_ + qw + lg * 4 + r] = inv_l[r];
    }
#pragma unroll
    for (int dj = 0; dj < 8; dj++)
#pragma unroll
      for (int r = 0; r < 4; r++) {
        int rowg = b * S_ + qw + lg * 4 + r;
        int colg = h * HD_ + dj * 16 + lr;
        attnO[(size_t)rowg * Dm + colg] = f2bf(o[dj][r] * inv_l[r]);
      }

    // zero-fill outW strict upper triangle for this wave's 16 rows
    {
      const int zc0 = nkt * 64;
      const int zn = (S_ - zc0) >> 2;
      f32x4 z = {0.f, 0.f, 0.f, 0.f};
      for (int rr = 0; rr < 16; rr++) {
        f32x4* base = (f32x4*)&outW[((size_t)bh * S_ + qw + rr) * S_ + zc0];
        for (int cc = l; cc < zn; cc += 64) __builtin_nontemporal_store(z, base + cc);
      }
    }

    // publish: linv + attnO visible, then signal
    __threadfence();
    __syncthreads();
    if (t == 0) {
      __hip_atomic_fetch_add(&flin[bh * 32 + qt], 1, __ATOMIC_RELEASE, __HIP_MEMORY_SCOPE_AGENT);
      __hip_atomic_fetch_add(&fmt[b * 16 + (qt >> 1)], 1, __ATOMIC_RELEASE,
                             __HIP_MEMORY_SCOPE_AGENT);
    }
    return;
  }

  if (bx < 2048) {
    // ======== attn_weights recompute + normalize (single q-tile), waits on linv ========
    const int bx2 = bx - 1024;
    const int qt = ((bx2 >> 5) + 16) & 31;   // mid-qt first (flags arrive earliest)
    const int bh = bx2 & 31;
    const int b = bh >> 4, h = bh & 15, kvh = h >> 2;
    const int qw = qt * 64 + w * 16;
    const int nkt = qt + 1;

    if (t == 0) {
      while (__hip_atomic_load(&flin[bh * 32 + qt], __ATOMIC_ACQUIRE,
                               __HIP_MEMORY_SCOPE_AGENT) < 1)
        __builtin_amdgcn_s_sleep(16);
    }
    __syncthreads();
    __threadfence();

    auto stageK = [&](int kt, int bufi) {
#pragma unroll
      for (int c = 0; c < 4; c++) {
        int row = c * 16 + (t >> 4), sl = t & 15;
        gl_lds16(qkv + (size_t)(b * S_ + kt * 64 + row) * 3072 + 2048 + kvh * HD_ +
                     ((sl ^ (row & 15)) << 3),
                 &smem[bufi * 8192 + c * 2048 + w * 512]);
      }
    };

    short8 qf[4];
#pragma unroll
    for (int kc = 0; kc < 4; kc++)
      qf[kc] = *(const short8*)&qkv[(size_t)(b * S_ + qw + lr) * 3072 + h * HD_ + kc * 32 + lg * 8];

    float invr[4];
#pragma unroll
    for (int r = 0; r < 4; r++) invr[r] = linv_g[(size_t)bh * S_ + qw + lg * 4 + r];

    stageK(0, 0);
    for (int kt = 0; kt < nkt; kt++) {
      const int cur = kt & 1;
      if (kt + 1 < nkt) {
        stageK(kt + 1, cur ^ 1);
        asm volatile("s_waitcnt vmcnt(4)" ::: "memory");
      } else {
        asm volatile("s_waitcnt vmcnt(0)" ::: "memory");
      }
      __builtin_amdgcn_s_barrier();

      f32x4 s[4];
#pragma unroll
      for (int ni = 0; ni < 4; ni++) s[ni] = (f32x4){0.f, 0.f, 0.f, 0.f};
#pragma unroll
      for (int kc = 0; kc < 4; kc++) {
        short8 kf[4];
#pragma unroll
        for (int ni = 0; ni < 4; ni++) {
          int row = ni * 16 + lr;
          kf[ni] = *(const short8*)((const char*)(smem + cur * 8192) + row * 256 +
                                    (((kc * 4 + lg) ^ (row & 15)) << 4));
        }
#pragma unroll
        for (int ni = 0; ni < 4; ni++)
          s[ni] = __builtin_amdgcn_mfma_f32_16x16x32_bf16(qf[kc], kf[ni], s[ni], 0, 0, 0);
      }

      const bool diag = (kt == nkt - 1);
#pragma unroll
      for (int ni = 0; ni < 4; ni++)
#pragma unroll
        for (int r = 0; r < 4; r++) {
          int colg = kt * 64 + ni * 16 + lr;
          int rowg = qw + lg * 4 + r;
          float p = exp2f(s[ni][r] * C2_) * invr[r];
          if (diag && colg > rowg) p = 0.f;
          outW[((size_t)bh * S_ + rowg) * S_ + colg] = p;
        }
      __builtin_amdgcn_s_barrier();
    }
    return;
  }

  // ======== Wo projection GEMM m-tile, waits on 32 attnO producers ========
  const int bx3 = bx - 2048;
  const int nid = (bx3 & 7) * 64 + (bx3 >> 3);   // XCD-chunked, 512%8==0
  const int n0 = (nid & 15) * 128, m0 = (nid >> 4) * 128;
  const int N = 2048, K = 2048;
  const int wr = w >> 1, wc = w & 1;
  const int srow = t >> 2, ssl = t & 3;
  const ushort_t* Agm = attnO;

  if (t == 0) {
    while (__hip_atomic_load(&fmt[nid >> 4], __ATOMIC_ACQUIRE, __HIP_MEMORY_SCOPE_AGENT) < 32)
      __builtin_amdgcn_s_sleep(16);
  }
  __syncthreads();
  __threadfence();

  auto stageG = [&](int kt, int bufi) {
    int r0 = srow, r1 = srow + 64;
    gl_lds16(Agm + (size_t)(m0 + r0) * K + kt + ((ssl ^ ((r0 >> 1) & 3)) << 3),
             &smem[bufi * 8192 + w * 512]);
    gl_lds16(Agm + (size_t)(m0 + r1) * K + kt + ((ssl ^ ((r1 >> 1) & 3)) << 3),
             &smem[bufi * 8192 + 2048 + w * 512]);
    gl_lds16(wto + (size_t)(n0 + r0) * K + kt + ((ssl ^ ((r0 >> 1) & 3)) << 3),
             &smem[bufi * 8192 + 4096 + w * 512]);
    gl_lds16(wto + (size_t)(n0 + r1) * K + kt + ((ssl ^ ((r1 >> 1) & 3)) << 3),
             &smem[bufi * 8192 + 4096 + 2048 + w * 512]);
  };

  f32x4 acc[4][4];
#pragma unroll
  for (int i = 0; i < 4; i++)
#pragma unroll
    for (int j = 0; j < 4; j++) acc[i][j] = (f32x4){0.f, 0.f, 0.f, 0.f};

  stageG(0, 0);
  const int nit = K / 32;
  for (int it = 0; it < nit; it++) {
    const int cur = it & 1;
    if (it + 1 < nit) {
      stageG((it + 1) * 32, cur ^ 1);
      asm volatile("s_waitcnt vmcnt(4)" ::: "memory");
    } else {
      asm volatile("s_waitcnt vmcnt(0)" ::: "memory");
    }
    __builtin_amdgcn_s_barrier();
    short8 af[4], bfr[4];
#pragma unroll
    for (int mi = 0; mi < 4; mi++) {
      int row = wr * 64 + mi * 16 + lr;
      af[mi] = *(const short8*)((const char*)(smem + cur * 8192) + row * 64 +
                                ((lg ^ ((row >> 1) & 3)) << 4));
    }
#pragma unroll
    for (int ni = 0; ni < 4; ni++) {
      int row = wc * 64 + ni * 16 + lr;
      bfr[ni] = *(const short8*)((const char*)(smem + cur * 8192 + 4096) + row * 64 +
                                 ((lg ^ ((row >> 1) & 3)) << 4));
    }
#pragma unroll
    for (int mi = 0; mi < 4; mi++)
#pragma unroll
      for (int ni = 0; ni < 4; ni++)
        acc[mi][ni] = __builtin_amdgcn_mfma_f32_16x16x32_bf16(af[mi], bfr[ni], acc[mi][ni], 0, 0, 0);
    __builtin_amdgcn_s_barrier();
  }
#pragma unroll
  for (int mi = 0; mi < 4; mi++)
#pragma unroll
    for (int ni = 0; ni < 4; ni++)
#pragma unroll
      for (int r = 0; r < 4; r++) {
        int row = m0 + wr * 64 + mi * 16 + lg * 4 + r;
        int col = n0 + wc * 64 + ni * 16 + lr;
        outO[(size_t)row * N + col] = acc[mi][ni][r];
      }
}

// ---------------- host ----------------
extern "C" void kernel_launch(void* const* d_in, const int* in_sizes, int n_in,
                              void* d_out, int out_size, void* d_ws, size_t ws_size,
                              hipStream_t stream) {
  const float* hs   = (const float*)d_in[0];
  const float* cosT = (const float*)d_in[1];
  const float* sinT = (const float*)d_in[2];
  // d_in[3] attention_mask: pure causal, applied analytically
  const float* Wq = (const float*)d_in[4];
  const float* bq = (const float*)d_in[5];
  const float* Wk = (const float*)d_in[6];
  const float* bk = (const float*)d_in[7];
  const float* Wv = (const float*)d_in[8];
  const float* bv = (const float*)d_in[9];
  const float* Wo = (const float*)d_in[10];

  char* ws = (char*)d_ws;
  ushort_t* hsb   = (ushort_t*)(ws);               // 16,777,216 B  [4096][2048] bf16
  ushort_t* wtqkv = (ushort_t*)(ws + 16777216);    // 12,582,912 B  [3072][2048] bf16 (Wq|Wk|Wv)^T
  ushort_t* wto   = (ushort_t*)(ws + 29360128);    //  8,388,608 B  [2048][2048] bf16 Wo^T
  ushort_t* qkv   = (ushort_t*)(ws + 37748736);    // 25,165,824 B  [4096][3072] bf16
  ushort_t* vt    = (ushort_t*)(ws + 62914560);    //  4,194,304 B  [8][128][2048] bf16
  float*    linv  = (float*)(ws + 67108864);       //     262,144 B [2][16][2048] f32
  int*      syncp = (int*)(ws + 67371008);         //       4,228 B ticket + flags
  ushort_t* attn  = (ushort_t*)(ws);               // reuse hsb region (dead after gemm_qkv)

  float* outO = (float*)d_out;            // [2,2048,2048] attn_out
  float* outW = outO + (size_t)8388608;   // [2,16,2048,2048] attn_weights

  prep_k<<<24577, 256, 0, stream>>>(hs, hsb, Wq, Wk, Wv, Wo, wtqkv, wto, syncp);
  gemm_qkv_k<<<768, 256, 0, stream>>>(hsb, wtqkv, qkv, bq, bk, bv, cosT, sinT, vt);
  fused_k<<<2560, 256, 0, stream>>>(qkv, vt, linv, attn, outW, wto, outO, syncp);
}

// Round 12
// 339.733 us; speedup vs baseline: 2.2512x; 2.2512x over previous
//
#include <hip/hip_runtime.h>

typedef unsigned short ushort_t;
typedef __attribute__((ext_vector_type(8))) short short8;   // 8 bf16 (4 VGPRs)
typedef __attribute__((ext_vector_type(4))) float f32x4;

#define S_  2048
#define Dm  2048
#define NH  16
#define NKV 4
#define HD_ 128
// SCALE * log2(e): exp(s*SCALE) == exp2(s*C2)
#define C2_ 0.12751879524465536f

__device__ __forceinline__ ushort_t f2bf(float f) {
  union { float f; unsigned u; } v; v.f = f;
  unsigned u = v.u;
  return (ushort_t)((u + 0x7FFFu + ((u >> 16) & 1u)) >> 16);   // RNE
}
__device__ __forceinline__ ushort_t f2bf2(float f) {            // round-half-up (2 VALU ops)
  union { float f; unsigned u; } v; v.f = f;
  return (ushort_t)((v.u + 0x8000u) >> 16);
}
__device__ __forceinline__ float bf2f(ushort_t h) {
  union { unsigned u; float f; } v; v.u = ((unsigned)h) << 16;
  return v.f;
}
__device__ __forceinline__ void gl_lds16(const void* g, void* l) {
  __builtin_amdgcn_global_load_lds((const __attribute__((address_space(1))) void*)g,
                                   (__attribute__((address_space(3))) void*)l, 16, 0, 0);
}

// ---------------- merged prep: bf16 convert (blocks <8192) + 4 weight transposes ----------------
__global__ void prep_k(const float* __restrict__ hs, ushort_t* __restrict__ hsb,
                       const float* __restrict__ Wq, const float* __restrict__ Wk,
                       const float* __restrict__ Wv, const float* __restrict__ Wo,
                       ushort_t* __restrict__ wtqkv, ushort_t* __restrict__ wto) {
  __shared__ float tile[32][33];
  const int id = blockIdx.x;
  if (id < 8192) {
    int i = id * 256 + threadIdx.x;
    float4 v = ((const float4*)hs)[i];
    union { ushort_t u[4]; uint2 v2; } o;
    o.u[0] = f2bf(v.x); o.u[1] = f2bf(v.y); o.u[2] = f2bf(v.z); o.u[3] = f2bf(v.w);
    *(uint2*)&hsb[(size_t)i * 4] = o.v2;
    return;
  }
  const int id2 = id - 8192;
  const int z = id2 >> 12, ky = (id2 >> 6) & 63, nx = id2 & 63;
  const float* src;
  ushort_t* dst;
  int N;
  switch (z) {
    case 0: src = Wq; dst = wtqkv; N = 2048; break;
    case 1: src = Wk; dst = wtqkv + (size_t)2048 * 2048; N = 512; break;
    case 2: src = Wv; dst = wtqkv + (size_t)2560 * 2048; N = 512; break;
    default: src = Wo; dst = wto; N = 2048; break;
  }
  int n0 = nx * 32, k0 = ky * 32;
  if (n0 >= N) return;
  int c = threadIdx.x & 31, r = threadIdx.x >> 5;   // r: 0..7
#pragma unroll
  for (int i = 0; i < 32; i += 8)
    tile[r + i][c] = src[(size_t)(k0 + r + i) * N + n0 + c];
  __syncthreads();
#pragma unroll
  for (int i = 0; i < 32; i += 8)
    dst[(size_t)(n0 + r + i) * 2048 + k0 + c] = f2bf(tile[c][r + i]);
}

// ---------------- GEMM QKV (dbuf, XCD swizzle) + bias + fused RoPE + fused V-transpose ----------
__global__ __launch_bounds__(256, 2) void gemm_qkv_k(
    const ushort_t* __restrict__ A, const ushort_t* __restrict__ Bt, ushort_t* __restrict__ C,
    const float* __restrict__ bq, const float* __restrict__ bk2, const float* __restrict__ bv,
    const float* __restrict__ cosT, const float* __restrict__ sinT, ushort_t* __restrict__ vt) {
  const int N = 3072, K = 2048;
  __shared__ ushort_t smem[16384];   // 32 KB: staging dbuf; later transpose tile / rope fbuf
  ushort_t* lA0 = smem;              // [2][4096], source-pre-swizzled: slot ^= (row>>1)&3
  ushort_t* lB0 = smem + 8192;
  const int lin = blockIdx.x;                    // 768 blocks
  const int nid = (lin & 7) * 96 + (lin >> 3);   // XCD-chunked swizzle (768%8==0)
  const int n0 = (nid % 24) * 128, m0 = (nid / 24) * 128;
  const int t = threadIdx.x;
  const int w = t >> 6, l = t & 63, lr = l & 15, lg = l >> 4;
  const int wr = w >> 1, wc = w & 1;
  const int srow = t >> 2, ssl = t & 3;

  auto stage = [&](int kt, int bufi) {
    int r0 = srow, r1 = srow + 64;
    gl_lds16(A + (size_t)(m0 + r0) * K + kt + ((ssl ^ ((r0 >> 1) & 3)) << 3),
             &lA0[bufi * 4096 + w * 512]);
    gl_lds16(A + (size_t)(m0 + r1) * K + kt + ((ssl ^ ((r1 >> 1) & 3)) << 3),
             &lA0[bufi * 4096 + 2048 + w * 512]);
    gl_lds16(Bt + (size_t)(n0 + r0) * K + kt + ((ssl ^ ((r0 >> 1) & 3)) << 3),
             &lB0[bufi * 4096 + w * 512]);
    gl_lds16(Bt + (size_t)(n0 + r1) * K + kt + ((ssl ^ ((r1 >> 1) & 3)) << 3),
             &lB0[bufi * 4096 + 2048 + w * 512]);
  };

  f32x4 acc[4][4];
#pragma unroll
  for (int i = 0; i < 4; i++)
#pragma unroll
    for (int j = 0; j < 4; j++) acc[i][j] = (f32x4){0.f, 0.f, 0.f, 0.f};

  stage(0, 0);
  const int nit = K / 32;   // 64
  for (int it = 0; it < nit; it++) {
    const int cur = it & 1;
    if (it + 1 < nit) {
      stage((it + 1) * 32, cur ^ 1);
      asm volatile("s_waitcnt vmcnt(4)" ::: "memory");   // current tile's 4 loads done
    } else {
      asm volatile("s_waitcnt vmcnt(0)" ::: "memory");
    }
    __builtin_amdgcn_s_barrier();
    short8 af[4], bfr[4];
#pragma unroll
    for (int mi = 0; mi < 4; mi++) {
      int row = wr * 64 + mi * 16 + lr;
      af[mi] = *(const short8*)((const char*)(lA0 + cur * 4096) + row * 64 +
                                ((lg ^ ((row >> 1) & 3)) << 4));
    }
#pragma unroll
    for (int ni = 0; ni < 4; ni++) {
      int row = wc * 64 + ni * 16 + lr;
      bfr[ni] = *(const short8*)((const char*)(lB0 + cur * 4096) + row * 64 +
                                 ((lg ^ ((row >> 1) & 3)) << 4));
    }
#pragma unroll
    for (int mi = 0; mi < 4; mi++)
#pragma unroll
      for (int ni = 0; ni < 4; ni++)
        acc[mi][ni] = __builtin_amdgcn_mfma_f32_16x16x32_bf16(af[mi], bfr[ni], acc[mi][ni], 0, 0, 0);
    __builtin_amdgcn_s_barrier();   // all waves done reading buf[cur] before restage
  }

  // epilogue: bias; RoPE (Q/K blocks) via partner-wave LDS exchange; V blocks also fill
  // the LDS transpose tile for the fused vt write.
  const bool isV = (n0 >= 2560);
  float* fbuf = (float*)smem;        // 16 KB, staging done
  const int pw_ = w ^ 1;             // partner wave: same wr, wc^1
#pragma unroll
  for (int mi = 0; mi < 4; mi++) {
    float vv[4][4];
#pragma unroll
    for (int ni = 0; ni < 4; ni++)
#pragma unroll
      for (int r = 0; r < 4; r++) {
        int col = n0 + wc * 64 + ni * 16 + lr;
        float bias = (col < 2048) ? bq[col] : (col < 2560) ? bk2[col - 2048] : bv[col - 2560];
        vv[ni][r] = acc[mi][ni][r] + bias;
      }
    if (!isV) {
      __syncthreads();
#pragma unroll
      for (int ni = 0; ni < 4; ni++)
#pragma unroll
        for (int r = 0; r < 4; r++)
          fbuf[w * 1024 + (lg * 4 + r) * 64 + ni * 16 + lr] = vv[ni][r];
      __syncthreads();
#pragma unroll
      for (int ni = 0; ni < 4; ni++)
#pragma unroll
        for (int r = 0; r < 4; r++) {
          float pv = fbuf[pw_ * 1024 + (lg * 4 + r) * 64 + ni * 16 + lr];
          int row = m0 + wr * 64 + mi * 16 + lg * 4 + r;   // = b*2048+s
          int d = wc * 64 + ni * 16 + lr;                  // 0..127 within head
          float c = cosT[(size_t)row * HD_ + d];
          float sn = sinT[(size_t)row * HD_ + d];
          vv[ni][r] = (wc == 0) ? vv[ni][r] * c - pv * sn : vv[ni][r] * c + pv * sn;
        }
    }
#pragma unroll
    for (int ni = 0; ni < 4; ni++)
#pragma unroll
      for (int r = 0; r < 4; r++) {
        int row = m0 + wr * 64 + mi * 16 + lg * 4 + r;
        int col = n0 + wc * 64 + ni * 16 + lr;
        ushort_t hv = f2bf(vv[ni][r]);
        C[(size_t)row * N + col] = hv;
        if (isV) {
          int colL = wc * 64 + ni * 16 + lr;            // d within head
          int rowL = wr * 64 + mi * 16 + lg * 4 + r;    // s within tile
          smem[colL * 128 + (rowL ^ ((colL & 7) << 4))] = hv;
        }
      }
  }
  if (isV) {
    __syncthreads();
    const int kvh = (n0 - 2560) >> 7;
    const int b = m0 >> 11, s0v = m0 & 2047;
    const size_t vbase = (size_t)(b * 4 + kvh) * 128;
#pragma unroll
    for (int j = 0; j < 8; j++) {
      int cid = j * 256 + t;
      int d = cid >> 4, sc = cid & 15;
      int rowStart = (sc * 8) ^ ((d & 7) << 4);
      short8 v8 = *(const short8*)&smem[d * 128 + rowStart];
      *(short8*)&vt[(vbase + d) * S_ + s0v + sc * 8] = v8;
    }
  }
}

// ---------------- fused causal GQA attention, single pass (m=0), 64-row q-tiles ----------------
// 1024 blocks, one q-tile each; single-buffered K/V (40KB LDS) -> 4 blocks/CU for TLP.
// qt = bx&31 interleave keeps per-CU load mixed under round-robin dispatch.
// Also zero-fills the strict upper triangle of outW for its q-rows.
__global__ __launch_bounds__(256, 4) void attn_k(
    const ushort_t* __restrict__ qkv, const ushort_t* __restrict__ vt,
    float* __restrict__ linv_g, ushort_t* __restrict__ attnO, float* __restrict__ outW) {
  __shared__ ushort_t lK[64 * 128];     // [k][d], 16 slots/row, slot ^= row&15   (16KB)
  __shared__ ushort_t lV[128 * 64];     // [d][k], 8 slots/row,  slot ^= row&7    (16KB)
  __shared__ ushort_t lP[4][16 * 64];   // per-wave P~ (16 rows), slot ^= row&7   (8KB)
  const int bx = blockIdx.x;            // 1024
  const int qt = bx & 31;               // interleaved q-tile index
  const int bh = bx >> 5;               // (b*16+h), 0..31
  const int b = bh >> 4, h = bh & 15;
  const int kvh = h >> 2;
  const int t = threadIdx.x, w = t >> 6, l = t & 63, lr = l & 15, lg = l >> 4;
  ushort_t* lPw = lP[w];

  const int qw = qt * 64 + w * 16;      // this wave's 16 q-rows
  const int nkt = qt + 1;               // 64-wide k-tiles in causal range

  auto stage = [&](int kt) {
#pragma unroll
    for (int c = 0; c < 4; c++) {
      int row = c * 16 + (t >> 4), sl = t & 15;
      gl_lds16(qkv + (size_t)(b * S_ + kt * 64 + row) * 3072 + 2048 + kvh * HD_ +
                   ((sl ^ (row & 15)) << 3),
               &lK[c * 2048 + w * 512]);
    }
#pragma unroll
    for (int c = 0; c < 4; c++) {
      int row = c * 32 + (t >> 3), sl = t & 7;
      gl_lds16(vt + (size_t)((b * 4 + kvh) * 128 + row) * S_ + kt * 64 +
                   ((sl ^ (row & 7)) << 3),
               &lV[c * 2048 + w * 512]);
    }
  };

  // Q fragments (A-frag: row=lane&15, k=(lane>>4)*8+i)
  short8 qf[4];
#pragma unroll
  for (int kc = 0; kc < 4; kc++)
    qf[kc] = *(const short8*)&qkv[(size_t)(b * S_ + qw + lr) * 3072 + h * HD_ + kc * 32 + lg * 8];

  float lsum[4];
  f32x4 o[8];
#pragma unroll
  for (int r = 0; r < 4; r++) lsum[r] = 0.f;
#pragma unroll
  for (int dj = 0; dj < 8; dj++) o[dj] = (f32x4){0.f, 0.f, 0.f, 0.f};

  for (int kt = 0; kt < nkt; kt++) {
    stage(kt);
    asm volatile("s_waitcnt vmcnt(0)" ::: "memory");   // this wave's 8 loads landed
    __builtin_amdgcn_s_barrier();                      // all waves' loads landed

    // S = Q K^T
    f32x4 s[4];
#pragma unroll
    for (int ni = 0; ni < 4; ni++) s[ni] = (f32x4){0.f, 0.f, 0.f, 0.f};
    __builtin_amdgcn_s_setprio(1);
#pragma unroll
    for (int kc = 0; kc < 4; kc++) {
      short8 kf[4];
#pragma unroll
      for (int ni = 0; ni < 4; ni++) {
        int row = ni * 16 + lr;
        kf[ni] = *(const short8*)((const char*)lK + row * 256 +
                                  (((kc * 4 + lg) ^ (row & 15)) << 4));
      }
#pragma unroll
      for (int ni = 0; ni < 4; ni++)
        s[ni] = __builtin_amdgcn_mfma_f32_16x16x32_bf16(qf[kc], kf[ni], s[ni], 0, 0, 0);
    }
    __builtin_amdgcn_s_setprio(0);

    // P~ = exp2(S*C2); mask only on the diagonal tile (separate clean path otherwise)
    if (kt == nkt - 1) {
#pragma unroll
      for (int ni = 0; ni < 4; ni++)
#pragma unroll
        for (int r = 0; r < 4; r++) {
          float p = exp2f(s[ni][r] * C2_);
          int colg = kt * 64 + ni * 16 + lr;
          int rowg = qw + lg * 4 + r;
          if (colg > rowg) p = 0.f;
          lsum[r] += p;
          int rowl = lg * 4 + r, col = ni * 16 + lr;
          lPw[rowl * 64 + (((col >> 3) ^ (rowl & 7)) << 3) + (col & 7)] = f2bf2(p);
        }
    } else {
#pragma unroll
      for (int ni = 0; ni < 4; ni++)
#pragma unroll
        for (int r = 0; r < 4; r++) {
          float p = exp2f(s[ni][r] * C2_);
          lsum[r] += p;
          int rowl = lg * 4 + r, col = ni * 16 + lr;
          lPw[rowl * 64 + (((col >> 3) ^ (rowl & 7)) << 3) + (col & 7)] = f2bf2(p);
        }
    }

    // O += P~ V
    __builtin_amdgcn_s_setprio(1);
#pragma unroll
    for (int kc = 0; kc < 2; kc++) {
      short8 pa;
      {
        int row = lr;
        pa = *(const short8*)((const char*)lPw + row * 128 + (((kc * 4 + lg) ^ (row & 7)) << 4));
      }
#pragma unroll
      for (int dj = 0; dj < 8; dj++) {
        int row = dj * 16 + lr;
        short8 vb = *(const short8*)((const char*)lV + row * 128 +
                                     (((kc * 4 + lg) ^ (row & 7)) << 4));
        o[dj] = __builtin_amdgcn_mfma_f32_16x16x32_bf16(pa, vb, o[dj], 0, 0, 0);
      }
    }
    __builtin_amdgcn_s_setprio(0);
    __builtin_amdgcn_s_barrier();   // all waves done reading lK/lV before restage
  }

  // row-sum reduce over the 16 lr lanes, write inv_l + normalized O
  float inv_l[4];
#pragma unroll
  for (int r = 0; r < 4; r++) {
    float sum = lsum[r];
#pragma unroll
    for (int off = 1; off < 16; off <<= 1) sum += __shfl_xor(sum, off);
    inv_l[r] = 1.f / sum;
    if (lr == 0) linv_g[(size_t)bh * S_ + qw + lg * 4 + r] = inv_l[r];
  }
#pragma unroll
  for (int dj = 0; dj < 8; dj++)
#pragma unroll
    for (int r = 0; r < 4; r++) {
      int rowg = b * S_ + qw + lg * 4 + r;
      int colg = h * HD_ + dj * 16 + lr;
      attnO[(size_t)rowg * Dm + colg] = f2bf(o[dj][r] * inv_l[r]);
    }

  // zero-fill outW strict upper triangle for this wave's 16 rows (cols >= nkt*64).
  {
    const int zc0 = nkt * 64;
    const int zn = (S_ - zc0) >> 2;   // float4 per row (multiple of 16, may be 0)
    f32x4 z = {0.f, 0.f, 0.f, 0.f};
    for (int rr = 0; rr < 16; rr++) {
      f32x4* base = (f32x4*)&outW[((size_t)bh * S_ + qw + rr) * S_ + zc0];
      for (int cc = l; cc < zn; cc += 64) __builtin_nontemporal_store(z, base + cc);
    }
  }
}

// ---------------- merged tail ----------------
// blocks [0,512):  Wo projection GEMM (dbuf, XCD swizzle)
// blocks [512,1024): attn_weights recompute+normalize (causal region only), XCD swizzle
__global__ __launch_bounds__(256, 2) void tail_k(
    const ushort_t* __restrict__ A, const ushort_t* __restrict__ Bt, float* __restrict__ outO,
    const ushort_t* __restrict__ qkv, const float* __restrict__ linv,
    float* __restrict__ outW) {
  __shared__ ushort_t sh[2][64 * 128];   // 32 KB
  const int bx = blockIdx.x;
  const int t = threadIdx.x;
  const int w = t >> 6, l = t & 63, lr = l & 15, lg = l >> 4;

  if (bx < 512) {
    // ---- Wo projection GEMM: M=4096, N=2048, K=2048 ----
    const int N = 2048, K = 2048;
    const int nid = (bx & 7) * 64 + (bx >> 3);   // XCD-chunked, 512%8==0
    const int n0 = (nid & 15) * 128, m0 = (nid >> 4) * 128;
    const int wr = w >> 1, wc = w & 1;
    const int srow = t >> 2, ssl = t & 3;

    auto stageG = [&](int kt, int bufi) {
      int r0 = srow, r1 = srow + 64;
      gl_lds16(A + (size_t)(m0 + r0) * K + kt + ((ssl ^ ((r0 >> 1) & 3)) << 3), &sh[bufi][w * 512]);
      gl_lds16(A + (size_t)(m0 + r1) * K + kt + ((ssl ^ ((r1 >> 1) & 3)) << 3),
               &sh[bufi][2048 + w * 512]);
      gl_lds16(Bt + (size_t)(n0 + r0) * K + kt + ((ssl ^ ((r0 >> 1) & 3)) << 3),
               &sh[bufi][4096 + w * 512]);
      gl_lds16(Bt + (size_t)(n0 + r1) * K + kt + ((ssl ^ ((r1 >> 1) & 3)) << 3),
               &sh[bufi][4096 + 2048 + w * 512]);
    };

    f32x4 acc[4][4];
#pragma unroll
    for (int i = 0; i < 4; i++)
#pragma unroll
      for (int j = 0; j < 4; j++) acc[i][j] = (f32x4){0.f, 0.f, 0.f, 0.f};

    stageG(0, 0);
    const int nit = K / 32;
    for (int it = 0; it < nit; it++) {
      const int cur = it & 1;
      if (it + 1 < nit) {
        stageG((it + 1) * 32, cur ^ 1);
        asm volatile("s_waitcnt vmcnt(4)" ::: "memory");
      } else {
        asm volatile("s_waitcnt vmcnt(0)" ::: "memory");
      }
      __builtin_amdgcn_s_barrier();
      short8 af[4], bfr[4];
#pragma unroll
      for (int mi = 0; mi < 4; mi++) {
        int row = wr * 64 + mi * 16 + lr;
        af[mi] =
            *(const short8*)((const char*)&sh[cur][0] + row * 64 + ((lg ^ ((row >> 1) & 3)) << 4));
      }
#pragma unroll
      for (int ni = 0; ni < 4; ni++) {
        int row = wc * 64 + ni * 16 + lr;
        bfr[ni] = *(const short8*)((const char*)&sh[cur][4096] + row * 64 +
                                   ((lg ^ ((row >> 1) & 3)) << 4));
      }
#pragma unroll
      for (int mi = 0; mi < 4; mi++)
#pragma unroll
        for (int ni = 0; ni < 4; ni++)
          acc[mi][ni] =
              __builtin_amdgcn_mfma_f32_16x16x32_bf16(af[mi], bfr[ni], acc[mi][ni], 0, 0, 0);
      __builtin_amdgcn_s_barrier();
    }
#pragma unroll
    for (int mi = 0; mi < 4; mi++)
#pragma unroll
      for (int ni = 0; ni < 4; ni++)
#pragma unroll
        for (int r = 0; r < 4; r++) {
          int row = m0 + wr * 64 + mi * 16 + lg * 4 + r;
          int col = n0 + wc * 64 + ni * 16 + lr;
          outO[(size_t)row * N + col] = acc[mi][ni][r];
        }
    return;
  }

  // ---- attn_weights recompute + normalize (causal region only) ----
  const int lin = bx - 512;                          // 0..511
  const int nid = (lin & 7) * 64 + (lin >> 3);       // XCD-chunked
  const int bh = nid >> 4;                           // (b*16+h), 0..31
  const int pi = nid & 15;                           // pair index 0..15
  const int b = bh >> 4, h = bh & 15;
  const int kvh = h >> 2;

  auto stageK = [&](int kt, int bufi) {
#pragma unroll
    for (int c = 0; c < 4; c++) {
      int row = c * 16 + (t >> 4), sl = t & 15;
      gl_lds16(qkv + (size_t)(b * S_ + kt * 64 + row) * 3072 + 2048 + kvh * HD_ +
                   ((sl ^ (row & 15)) << 3),
               &sh[bufi][c * 2048 + w * 512]);
    }
  };

  for (int sel = 0; sel < 2; sel++) {
    const int qt = sel ? (31 - pi) : pi;   // 64-row q-tile, 0..31
    const int qw = qt * 64 + w * 16;       // this wave's 16 q-rows
    const int nkt = qt + 1;

    short8 qf[4];
#pragma unroll
    for (int kc = 0; kc < 4; kc++)
      qf[kc] = *(const short8*)&qkv[(size_t)(b * S_ + qw + lr) * 3072 + h * HD_ + kc * 32 + lg * 8];

    float invr[4];
#pragma unroll
    for (int r = 0; r < 4; r++) invr[r] = linv[(size_t)bh * S_ + qw + lg * 4 + r];

    stageK(0, 0);
    for (int kt = 0; kt < nkt; kt++) {
      const int cur = kt & 1;
      if (kt + 1 < nkt) {
        stageK(kt + 1, cur ^ 1);
        asm volatile("s_waitcnt vmcnt(4)" ::: "memory");
      } else {
        asm volatile("s_waitcnt vmcnt(0)" ::: "memory");
      }
      __builtin_amdgcn_s_barrier();

      f32x4 s[4];
#pragma unroll
      for (int ni = 0; ni < 4; ni++) s[ni] = (f32x4){0.f, 0.f, 0.f, 0.f};
#pragma unroll
      for (int kc = 0; kc < 4; kc++) {
        short8 kf[4];
#pragma unroll
        for (int ni = 0; ni < 4; ni++) {
          int row = ni * 16 + lr;
          kf[ni] = *(const short8*)((const char*)sh[cur] + row * 256 +
                                    (((kc * 4 + lg) ^ (row & 15)) << 4));
        }
#pragma unroll
        for (int ni = 0; ni < 4; ni++)
          s[ni] = __builtin_amdgcn_mfma_f32_16x16x32_bf16(qf[kc], kf[ni], s[ni], 0, 0, 0);
      }

      const bool diag = (kt == nkt - 1);
#pragma unroll
      for (int ni = 0; ni < 4; ni++)
#pragma unroll
        for (int r = 0; r < 4; r++) {
          int colg = kt * 64 + ni * 16 + lr;
          int rowg = qw + lg * 4 + r;
          float p = exp2f(s[ni][r] * C2_) * invr[r];
          if (diag && colg > rowg) p = 0.f;
          outW[((size_t)bh * S_ + rowg) * S_ + colg] = p;
        }
      __builtin_amdgcn_s_barrier();
    }
  }
}

// ---------------- host ----------------
extern "C" void kernel_launch(void* const* d_in, const int* in_sizes, int n_in,
                              void* d_out, int out_size, void* d_ws, size_t ws_size,
                              hipStream_t stream) {
  const float* hs   = (const float*)d_in[0];
  const float* cosT = (const float*)d_in[1];
  const float* sinT = (const float*)d_in[2];
  // d_in[3] attention_mask: pure causal, applied analytically
  const float* Wq = (const float*)d_in[4];
  const float* bq = (const float*)d_in[5];
  const float* Wk = (const float*)d_in[6];
  const float* bk = (const float*)d_in[7];
  const float* Wv = (const float*)d_in[8];
  const float* bv = (const float*)d_in[9];
  const float* Wo = (const float*)d_in[10];

  char* ws = (char*)d_ws;
  ushort_t* hsb   = (ushort_t*)(ws);               // 16,777,216 B  [4096][2048] bf16
  ushort_t* wtqkv = (ushort_t*)(ws + 16777216);    // 12,582,912 B  [3072][2048] bf16 (Wq|Wk|Wv)^T
  ushort_t* wto   = (ushort_t*)(ws + 29360128);    //  8,388,608 B  [2048][2048] bf16 Wo^T
  ushort_t* qkv   = (ushort_t*)(ws + 37748736);    // 25,165,824 B  [4096][3072] bf16
  ushort_t* vt    = (ushort_t*)(ws + 62914560);    //  4,194,304 B  [8][128][2048] bf16
  float*    linv  = (float*)(ws + 67108864);       //     262,144 B [2][16][2048] f32
  ushort_t* attn  = (ushort_t*)(ws);               // reuse hsb region (dead after gemm_qkv)

  float* outO = (float*)d_out;            // [2,2048,2048] attn_out
  float* outW = outO + (size_t)8388608;   // [2,16,2048,2048] attn_weights

  prep_k<<<8192 + 16384, 256, 0, stream>>>(hs, hsb, Wq, Wk, Wv, Wo, wtqkv, wto);
  gemm_qkv_k<<<768, 256, 0, stream>>>(hsb, wtqkv, qkv, bq, bk, bv, cosT, sinT, vt);
  attn_k<<<1024, 256, 0, stream>>>(qkv, vt, linv, attn, outW);
  tail_k<<<1024, 256, 0, stream>>>(attn, wto, outO, qkv, linv, outW);
}

// Round 13
// 305.960 us; speedup vs baseline: 2.4997x; 1.1104x over previous
//
#include <hip/hip_runtime.h>

typedef unsigned short ushort_t;
typedef __attribute__((ext_vector_type(8))) short short8;   // 8 bf16 (4 VGPRs)
typedef __attribute__((ext_vector_type(4))) float f32x4;

#define S_  2048
#define Dm  2048
#define NH  16
#define NKV 4
#define HD_ 128
// SCALE * log2(e): exp(s*SCALE) == exp2(s*C2)
#define C2_ 0.12751879524465536f

__device__ __forceinline__ ushort_t f2bf(float f) {
  union { float f; unsigned u; } v; v.f = f;
  unsigned u = v.u;
  return (ushort_t)((u + 0x7FFFu + ((u >> 16) & 1u)) >> 16);   // RNE
}
__device__ __forceinline__ ushort_t f2bf2(float f) {            // round-half-up (2 VALU ops)
  union { float f; unsigned u; } v; v.f = f;
  return (ushort_t)((v.u + 0x8000u) >> 16);
}
__device__ __forceinline__ float bf2f(ushort_t h) {
  union { unsigned u; float f; } v; v.u = ((unsigned)h) << 16;
  return v.f;
}
__device__ __forceinline__ void gl_lds16(const void* g, void* l) {
  __builtin_amdgcn_global_load_lds((const __attribute__((address_space(1))) void*)g,
                                   (__attribute__((address_space(3))) void*)l, 16, 0, 0);
}

// ---------------- merged prep: bf16 convert (blocks <8192) + 4 weight transposes ----------------
__global__ void prep_k(const float* __restrict__ hs, ushort_t* __restrict__ hsb,
                       const float* __restrict__ Wq, const float* __restrict__ Wk,
                       const float* __restrict__ Wv, const float* __restrict__ Wo,
                       ushort_t* __restrict__ wtqkv, ushort_t* __restrict__ wto) {
  __shared__ float tile[32][33];
  const int id = blockIdx.x;
  if (id < 8192) {
    int i = id * 256 + threadIdx.x;
    float4 v = ((const float4*)hs)[i];
    union { ushort_t u[4]; uint2 v2; } o;
    o.u[0] = f2bf(v.x); o.u[1] = f2bf(v.y); o.u[2] = f2bf(v.z); o.u[3] = f2bf(v.w);
    *(uint2*)&hsb[(size_t)i * 4] = o.v2;
    return;
  }
  const int id2 = id - 8192;
  const int z = id2 >> 12, ky = (id2 >> 6) & 63, nx = id2 & 63;
  const float* src;
  ushort_t* dst;
  int N;
  switch (z) {
    case 0: src = Wq; dst = wtqkv; N = 2048; break;
    case 1: src = Wk; dst = wtqkv + (size_t)2048 * 2048; N = 512; break;
    case 2: src = Wv; dst = wtqkv + (size_t)2560 * 2048; N = 512; break;
    default: src = Wo; dst = wto; N = 2048; break;
  }
  int n0 = nx * 32, k0 = ky * 32;
  if (n0 >= N) return;
  int c = threadIdx.x & 31, r = threadIdx.x >> 5;   // r: 0..7
#pragma unroll
  for (int i = 0; i < 32; i += 8)
    tile[r + i][c] = src[(size_t)(k0 + r + i) * N + n0 + c];
  __syncthreads();
#pragma unroll
  for (int i = 0; i < 32; i += 8)
    dst[(size_t)(n0 + r + i) * 2048 + k0 + c] = f2bf(tile[c][r + i]);
}

// ---------------- GEMM QKV (dbuf, XCD swizzle) + bias + fused RoPE + fused V-transpose ----------
__global__ __launch_bounds__(256, 2) void gemm_qkv_k(
    const ushort_t* __restrict__ A, const ushort_t* __restrict__ Bt, ushort_t* __restrict__ C,
    const float* __restrict__ bq, const float* __restrict__ bk2, const float* __restrict__ bv,
    const float* __restrict__ cosT, const float* __restrict__ sinT, ushort_t* __restrict__ vt) {
  const int N = 3072, K = 2048;
  __shared__ ushort_t smem[16384];   // 32 KB: staging dbuf; later transpose tile / rope fbuf
  ushort_t* lA0 = smem;              // [2][4096], source-pre-swizzled: slot ^= (row>>1)&3
  ushort_t* lB0 = smem + 8192;
  const int lin = blockIdx.x;                    // 768 blocks
  const int nid = (lin & 7) * 96 + (lin >> 3);   // XCD-chunked swizzle (768%8==0)
  const int n0 = (nid % 24) * 128, m0 = (nid / 24) * 128;
  const int t = threadIdx.x;
  const int w = t >> 6, l = t & 63, lr = l & 15, lg = l >> 4;
  const int wr = w >> 1, wc = w & 1;
  const int srow = t >> 2, ssl = t & 3;

  auto stage = [&](int kt, int bufi) {
    int r0 = srow, r1 = srow + 64;
    gl_lds16(A + (size_t)(m0 + r0) * K + kt + ((ssl ^ ((r0 >> 1) & 3)) << 3),
             &lA0[bufi * 4096 + w * 512]);
    gl_lds16(A + (size_t)(m0 + r1) * K + kt + ((ssl ^ ((r1 >> 1) & 3)) << 3),
             &lA0[bufi * 4096 + 2048 + w * 512]);
    gl_lds16(Bt + (size_t)(n0 + r0) * K + kt + ((ssl ^ ((r0 >> 1) & 3)) << 3),
             &lB0[bufi * 4096 + w * 512]);
    gl_lds16(Bt + (size_t)(n0 + r1) * K + kt + ((ssl ^ ((r1 >> 1) & 3)) << 3),
             &lB0[bufi * 4096 + 2048 + w * 512]);
  };

  f32x4 acc[4][4];
#pragma unroll
  for (int i = 0; i < 4; i++)
#pragma unroll
    for (int j = 0; j < 4; j++) acc[i][j] = (f32x4){0.f, 0.f, 0.f, 0.f};

  stage(0, 0);
  const int nit = K / 32;   // 64
  for (int it = 0; it < nit; it++) {
    const int cur = it & 1;
    if (it + 1 < nit) {
      stage((it + 1) * 32, cur ^ 1);
      asm volatile("s_waitcnt vmcnt(4)" ::: "memory");   // current tile's 4 loads done
    } else {
      asm volatile("s_waitcnt vmcnt(0)" ::: "memory");
    }
    __builtin_amdgcn_s_barrier();
    short8 af[4], bfr[4];
#pragma unroll
    for (int mi = 0; mi < 4; mi++) {
      int row = wr * 64 + mi * 16 + lr;
      af[mi] = *(const short8*)((const char*)(lA0 + cur * 4096) + row * 64 +
                                ((lg ^ ((row >> 1) & 3)) << 4));
    }
#pragma unroll
    for (int ni = 0; ni < 4; ni++) {
      int row = wc * 64 + ni * 16 + lr;
      bfr[ni] = *(const short8*)((const char*)(lB0 + cur * 4096) + row * 64 +
                                 ((lg ^ ((row >> 1) & 3)) << 4));
    }
#pragma unroll
    for (int mi = 0; mi < 4; mi++)
#pragma unroll
      for (int ni = 0; ni < 4; ni++)
        acc[mi][ni] = __builtin_amdgcn_mfma_f32_16x16x32_bf16(af[mi], bfr[ni], acc[mi][ni], 0, 0, 0);
    __builtin_amdgcn_s_barrier();   // all waves done reading buf[cur] before restage
  }

  // epilogue: bias; RoPE (Q/K blocks) via partner-wave LDS exchange; V blocks also fill
  // the LDS transpose tile for the fused vt write.
  const bool isV = (n0 >= 2560);
  float* fbuf = (float*)smem;        // 16 KB, staging done
  const int pw_ = w ^ 1;             // partner wave: same wr, wc^1
#pragma unroll
  for (int mi = 0; mi < 4; mi++) {
    float vv[4][4];
#pragma unroll
    for (int ni = 0; ni < 4; ni++)
#pragma unroll
      for (int r = 0; r < 4; r++) {
        int col = n0 + wc * 64 + ni * 16 + lr;
        float bias = (col < 2048) ? bq[col] : (col < 2560) ? bk2[col - 2048] : bv[col - 2560];
        vv[ni][r] = acc[mi][ni][r] + bias;
      }
    if (!isV) {
      __syncthreads();
#pragma unroll
      for (int ni = 0; ni < 4; ni++)
#pragma unroll
        for (int r = 0; r < 4; r++)
          fbuf[w * 1024 + (lg * 4 + r) * 64 + ni * 16 + lr] = vv[ni][r];
      __syncthreads();
#pragma unroll
      for (int ni = 0; ni < 4; ni++)
#pragma unroll
        for (int r = 0; r < 4; r++) {
          float pv = fbuf[pw_ * 1024 + (lg * 4 + r) * 64 + ni * 16 + lr];
          int row = m0 + wr * 64 + mi * 16 + lg * 4 + r;   // = b*2048+s
          int d = wc * 64 + ni * 16 + lr;                  // 0..127 within head
          float c = cosT[(size_t)row * HD_ + d];
          float sn = sinT[(size_t)row * HD_ + d];
          vv[ni][r] = (wc == 0) ? vv[ni][r] * c - pv * sn : vv[ni][r] * c + pv * sn;
        }
    }
#pragma unroll
    for (int ni = 0; ni < 4; ni++)
#pragma unroll
      for (int r = 0; r < 4; r++) {
        int row = m0 + wr * 64 + mi * 16 + lg * 4 + r;
        int col = n0 + wc * 64 + ni * 16 + lr;
        ushort_t hv = f2bf(vv[ni][r]);
        C[(size_t)row * N + col] = hv;
        if (isV) {
          int colL = wc * 64 + ni * 16 + lr;            // d within head
          int rowL = wr * 64 + mi * 16 + lg * 4 + r;    // s within tile
          smem[colL * 128 + (rowL ^ ((colL & 7) << 4))] = hv;
        }
      }
  }
  if (isV) {
    __syncthreads();
    const int kvh = (n0 - 2560) >> 7;
    const int b = m0 >> 11, s0v = m0 & 2047;
    const size_t vbase = (size_t)(b * 4 + kvh) * 128;
#pragma unroll
    for (int j = 0; j < 8; j++) {
      int cid = j * 256 + t;
      int d = cid >> 4, sc = cid & 15;
      int rowStart = (sc * 8) ^ ((d & 7) << 4);
      short8 v8 = *(const short8*)&smem[d * 128 + rowStart];
      *(short8*)&vt[(vbase + d) * S_ + s0v + sc * 8] = v8;
    }
  }
}

// ---------------- fused causal GQA attention, single pass (m=0), 64-row q-tiles ----------------
// 512 blocks (XCD-chunk swizzled); block handles q-tiles {pi, 31-pi}: constant 33 k-tiles.
// Also zero-fills the strict upper triangle of outW for its q-rows (hides under compute).
__global__ __launch_bounds__(256, 2) void attn_k(
    const ushort_t* __restrict__ qkv, const ushort_t* __restrict__ vt,
    float* __restrict__ linv_g, ushort_t* __restrict__ attnO, float* __restrict__ outW) {
  __shared__ ushort_t lK[2][64 * 128];   // [k][d], 16 slots/row, slot ^= row&15
  __shared__ ushort_t lV[2][128 * 64];   // [d][k], 8 slots/row,  slot ^= row&7
  __shared__ ushort_t lP[4][16 * 64];    // per-wave P~ (16 rows), slot ^= row&7
  const int nid = (blockIdx.x & 7) * 64 + (blockIdx.x >> 3);   // 512%8==0, bijective
  const int pairI = nid & 15, h = (nid >> 4) & 15, b = nid >> 8;
  const int kvh = h >> 2;
  const int t = threadIdx.x, w = t >> 6, l = t & 63, lr = l & 15, lg = l >> 4;
  ushort_t* lPw = lP[w];

  auto stage = [&](int kt, int bufi) {
#pragma unroll
    for (int c = 0; c < 4; c++) {
      int row = c * 16 + (t >> 4), sl = t & 15;
      gl_lds16(qkv + (size_t)(b * S_ + kt * 64 + row) * 3072 + 2048 + kvh * HD_ +
                   ((sl ^ (row & 15)) << 3),
               &lK[bufi][c * 2048 + w * 512]);
    }
#pragma unroll
    for (int c = 0; c < 4; c++) {
      int row = c * 32 + (t >> 3), sl = t & 7;
      gl_lds16(vt + (size_t)((b * 4 + kvh) * 128 + row) * S_ + kt * 64 +
                   ((sl ^ (row & 7)) << 3),
               &lV[bufi][c * 2048 + w * 512]);
    }
  };

  for (int sel = 0; sel < 2; sel++) {
    const int qt = sel ? (31 - pairI) : pairI;   // 64-row q-tile index, 0..31
    const int qw = qt * 64 + w * 16;             // this wave's 16 q-rows
    const int nkt = qt + 1;                      // 64-wide k-tiles in causal range

    // Q fragments (A-frag: row=lane&15, k=(lane>>4)*8+i)
    short8 qf[4];
#pragma unroll
    for (int kc = 0; kc < 4; kc++)
      qf[kc] = *(const short8*)&qkv[(size_t)(b * S_ + qw + lr) * 3072 + h * HD_ + kc * 32 + lg * 8];

    float lsum[4];
    f32x4 o[8];
#pragma unroll
    for (int r = 0; r < 4; r++) lsum[r] = 0.f;
#pragma unroll
    for (int dj = 0; dj < 8; dj++) o[dj] = (f32x4){0.f, 0.f, 0.f, 0.f};

    stage(0, 0);
    for (int kt = 0; kt < nkt; kt++) {
      const int cur = kt & 1;
      if (kt + 1 < nkt) {
        stage(kt + 1, cur ^ 1);
        asm volatile("s_waitcnt vmcnt(8)" ::: "memory");   // current tile's 8 loads done
      } else {
        asm volatile("s_waitcnt vmcnt(0)" ::: "memory");
      }
      __builtin_amdgcn_s_barrier();

      // S = Q K^T
      f32x4 s[4];
#pragma unroll
      for (int ni = 0; ni < 4; ni++) s[ni] = (f32x4){0.f, 0.f, 0.f, 0.f};
      __builtin_amdgcn_s_setprio(1);
#pragma unroll
      for (int kc = 0; kc < 4; kc++) {
        short8 kf[4];
#pragma unroll
        for (int ni = 0; ni < 4; ni++) {
          int row = ni * 16 + lr;
          kf[ni] = *(const short8*)((const char*)lK[cur] + row * 256 +
                                    (((kc * 4 + lg) ^ (row & 15)) << 4));
        }
#pragma unroll
        for (int ni = 0; ni < 4; ni++)
          s[ni] = __builtin_amdgcn_mfma_f32_16x16x32_bf16(qf[kc], kf[ni], s[ni], 0, 0, 0);
      }
      __builtin_amdgcn_s_setprio(0);

      // P~ = exp2(S*C2); mask only on the diagonal tile (separate clean path otherwise)
      if (kt == nkt - 1) {
#pragma unroll
        for (int ni = 0; ni < 4; ni++)
#pragma unroll
          for (int r = 0; r < 4; r++) {
            float p = exp2f(s[ni][r] * C2_);
            int colg = kt * 64 + ni * 16 + lr;
            int rowg = qw + lg * 4 + r;
            if (colg > rowg) p = 0.f;
            lsum[r] += p;
            int rowl = lg * 4 + r, col = ni * 16 + lr;
            lPw[rowl * 64 + (((col >> 3) ^ (rowl & 7)) << 3) + (col & 7)] = f2bf2(p);
          }
      } else {
#pragma unroll
        for (int ni = 0; ni < 4; ni++)
#pragma unroll
          for (int r = 0; r < 4; r++) {
            float p = exp2f(s[ni][r] * C2_);
            lsum[r] += p;
            int rowl = lg * 4 + r, col = ni * 16 + lr;
            lPw[rowl * 64 + (((col >> 3) ^ (rowl & 7)) << 3) + (col & 7)] = f2bf2(p);
          }
      }

      // O += P~ V
      __builtin_amdgcn_s_setprio(1);
#pragma unroll
      for (int kc = 0; kc < 2; kc++) {
        short8 pa;
        {
          int row = lr;
          pa = *(const short8*)((const char*)lPw + row * 128 + (((kc * 4 + lg) ^ (row & 7)) << 4));
        }
#pragma unroll
        for (int dj = 0; dj < 8; dj++) {
          int row = dj * 16 + lr;
          short8 vb = *(const short8*)((const char*)lV[cur] + row * 128 +
                                       (((kc * 4 + lg) ^ (row & 7)) << 4));
          o[dj] = __builtin_amdgcn_mfma_f32_16x16x32_bf16(pa, vb, o[dj], 0, 0, 0);
        }
      }
      __builtin_amdgcn_s_setprio(0);
      __builtin_amdgcn_s_barrier();   // all waves done reading buf[cur] before restage
    }

    // row-sum reduce over the 16 lr lanes, write inv_l + normalized O
    float inv_l[4];
#pragma unroll
    for (int r = 0; r < 4; r++) {
      float sum = lsum[r];
#pragma unroll
      for (int off = 1; off < 16; off <<= 1) sum += __shfl_xor(sum, off);
      inv_l[r] = 1.f / sum;
      if (lr == 0) linv_g[(size_t)(b * NH + h) * S_ + qw + lg * 4 + r] = inv_l[r];
    }
#pragma unroll
    for (int dj = 0; dj < 8; dj++)
#pragma unroll
      for (int r = 0; r < 4; r++) {
        int rowg = b * S_ + qw + lg * 4 + r;
        int colg = h * HD_ + dj * 16 + lr;
        attnO[(size_t)rowg * Dm + colg] = f2bf(o[dj][r] * inv_l[r]);
      }

    // zero-fill outW strict upper triangle for this wave's 16 rows (cols >= nkt*64).
    {
      const int zc0 = nkt * 64;
      const int zn = (S_ - zc0) >> 2;   // float4 per row (multiple of 16, may be 0)
      f32x4 z = {0.f, 0.f, 0.f, 0.f};
      const int bh = b * NH + h;
      for (int rr = 0; rr < 16; rr++) {
        f32x4* base = (f32x4*)&outW[((size_t)bh * S_ + qw + rr) * S_ + zc0];
        for (int cc = l; cc < zn; cc += 64) __builtin_nontemporal_store(z, base + cc);
      }
    }
  }
}

// ---------------- merged tail (4 blocks/CU so GEMM + norm co-reside) ----------------
// blocks [0,512):  Wo projection GEMM (dbuf, XCD swizzle)
// blocks [512,1024): attn_weights recompute+normalize (causal region only), XCD swizzle
__global__ __launch_bounds__(256, 4) void tail_k(
    const ushort_t* __restrict__ A, const ushort_t* __restrict__ Bt, float* __restrict__ outO,
    const ushort_t* __restrict__ qkv, const float* __restrict__ linv,
    float* __restrict__ outW) {
  __shared__ ushort_t sh[2][64 * 128];   // 32 KB -> 4 blocks/CU = 128 KB of 160 KB
  const int bx = blockIdx.x;
  const int t = threadIdx.x;
  const int w = t >> 6, l = t & 63, lr = l & 15, lg = l >> 4;

  if (bx < 512) {
    // ---- Wo projection GEMM: M=4096, N=2048, K=2048 ----
    const int N = 2048, K = 2048;
    const int nid = (bx & 7) * 64 + (bx >> 3);   // XCD-chunked, 512%8==0
    const int n0 = (nid & 15) * 128, m0 = (nid >> 4) * 128;
    const int wr = w >> 1, wc = w & 1;
    const int srow = t >> 2, ssl = t & 3;

    auto stageG = [&](int kt, int bufi) {
      int r0 = srow, r1 = srow + 64;
      gl_lds16(A + (size_t)(m0 + r0) * K + kt + ((ssl ^ ((r0 >> 1) & 3)) << 3), &sh[bufi][w * 512]);
      gl_lds16(A + (size_t)(m0 + r1) * K + kt + ((ssl ^ ((r1 >> 1) & 3)) << 3),
               &sh[bufi][2048 + w * 512]);
      gl_lds16(Bt + (size_t)(n0 + r0) * K + kt + ((ssl ^ ((r0 >> 1) & 3)) << 3),
               &sh[bufi][4096 + w * 512]);
      gl_lds16(Bt + (size_t)(n0 + r1) * K + kt + ((ssl ^ ((r1 >> 1) & 3)) << 3),
               &sh[bufi][4096 + 2048 + w * 512]);
    };

    f32x4 acc[4][4];
#pragma unroll
    for (int i = 0; i < 4; i++)
#pragma unroll
      for (int j = 0; j < 4; j++) acc[i][j] = (f32x4){0.f, 0.f, 0.f, 0.f};

    stageG(0, 0);
    const int nit = K / 32;
    for (int it = 0; it < nit; it++) {
      const int cur = it & 1;
      if (it + 1 < nit) {
        stageG((it + 1) * 32, cur ^ 1);
        asm volatile("s_waitcnt vmcnt(4)" ::: "memory");
      } else {
        asm volatile("s_waitcnt vmcnt(0)" ::: "memory");
      }
      __builtin_amdgcn_s_barrier();
      short8 af[4], bfr[4];
#pragma unroll
      for (int mi = 0; mi < 4; mi++) {
        int row = wr * 64 + mi * 16 + lr;
        af[mi] =
            *(const short8*)((const char*)&sh[cur][0] + row * 64 + ((lg ^ ((row >> 1) & 3)) << 4));
      }
#pragma unroll
      for (int ni = 0; ni < 4; ni++) {
        int row = wc * 64 + ni * 16 + lr;
        bfr[ni] = *(const short8*)((const char*)&sh[cur][4096] + row * 64 +
                                   ((lg ^ ((row >> 1) & 3)) << 4));
      }
#pragma unroll
      for (int mi = 0; mi < 4; mi++)
#pragma unroll
        for (int ni = 0; ni < 4; ni++)
          acc[mi][ni] =
              __builtin_amdgcn_mfma_f32_16x16x32_bf16(af[mi], bfr[ni], acc[mi][ni], 0, 0, 0);
      __builtin_amdgcn_s_barrier();
    }
#pragma unroll
    for (int mi = 0; mi < 4; mi++)
#pragma unroll
      for (int ni = 0; ni < 4; ni++)
#pragma unroll
        for (int r = 0; r < 4; r++) {
          int row = m0 + wr * 64 + mi * 16 + lg * 4 + r;
          int col = n0 + wc * 64 + ni * 16 + lr;
          outO[(size_t)row * N + col] = acc[mi][ni][r];
        }
    return;
  }

  // ---- attn_weights recompute + normalize (causal region only) ----
  const int lin = bx - 512;                          // 0..511
  const int nid = (lin & 7) * 64 + (lin >> 3);       // XCD-chunked
  const int bh = nid >> 4;                           // (b*16+h), 0..31
  const int pi = nid & 15;                           // pair index 0..15
  const int b = bh >> 4, h = bh & 15;
  const int kvh = h >> 2;

  auto stageK = [&](int kt, int bufi) {
#pragma unroll
    for (int c = 0; c < 4; c++) {
      int row = c * 16 + (t >> 4), sl = t & 15;
      gl_lds16(qkv + (size_t)(b * S_ + kt * 64 + row) * 3072 + 2048 + kvh * HD_ +
                   ((sl ^ (row & 15)) << 3),
               &sh[bufi][c * 2048 + w * 512]);
    }
  };

  for (int sel = 0; sel < 2; sel++) {
    const int qt = sel ? (31 - pi) : pi;   // 64-row q-tile, 0..31
    const int qw = qt * 64 + w * 16;       // this wave's 16 q-rows
    const int nkt = qt + 1;

    short8 qf[4];
#pragma unroll
    for (int kc = 0; kc < 4; kc++)
      qf[kc] = *(const short8*)&qkv[(size_t)(b * S_ + qw + lr) * 3072 + h * HD_ + kc * 32 + lg * 8];

    float invr[4];
#pragma unroll
    for (int r = 0; r < 4; r++) invr[r] = linv[(size_t)bh * S_ + qw + lg * 4 + r];

    stageK(0, 0);
    for (int kt = 0; kt < nkt; kt++) {
      const int cur = kt & 1;
      if (kt + 1 < nkt) {
        stageK(kt + 1, cur ^ 1);
        asm volatile("s_waitcnt vmcnt(4)" ::: "memory");
      } else {
        asm volatile("s_waitcnt vmcnt(0)" ::: "memory");
      }
      __builtin_amdgcn_s_barrier();

      f32x4 s[4];
#pragma unroll
      for (int ni = 0; ni < 4; ni++) s[ni] = (f32x4){0.f, 0.f, 0.f, 0.f};
#pragma unroll
      for (int kc = 0; kc < 4; kc++) {
        short8 kf[4];
#pragma unroll
        for (int ni = 0; ni < 4; ni++) {
          int row = ni * 16 + lr;
          kf[ni] = *(const short8*)((const char*)sh[cur] + row * 256 +
                                    (((kc * 4 + lg) ^ (row & 15)) << 4));
        }
#pragma unroll
        for (int ni = 0; ni < 4; ni++)
          s[ni] = __builtin_amdgcn_mfma_f32_16x16x32_bf16(qf[kc], kf[ni], s[ni], 0, 0, 0);
      }

      const bool diag = (kt == nkt - 1);
#pragma unroll
      for (int ni = 0; ni < 4; ni++)
#pragma unroll
        for (int r = 0; r < 4; r++) {
          int colg = kt * 64 + ni * 16 + lr;
          int rowg = qw + lg * 4 + r;
          float p = exp2f(s[ni][r] * C2_) * invr[r];
          if (diag && colg > rowg) p = 0.f;
          outW[((size_t)bh * S_ + rowg) * S_ + colg] = p;
        }
      __builtin_amdgcn_s_barrier();
    }
  }
}

// ---------------- host ----------------
extern "C" void kernel_launch(void* const* d_in, const int* in_sizes, int n_in,
                              void* d_out, int out_size, void* d_ws, size_t ws_size,
                              hipStream_t stream) {
  const float* hs   = (const float*)d_in[0];
  const float* cosT = (const float*)d_in[1];
  const float* sinT = (const float*)d_in[2];
  // d_in[3] attention_mask: pure causal, applied analytically
  const float* Wq = (const float*)d_in[4];
  const float* bq = (const float*)d_in[5];
  const float* Wk = (const float*)d_in[6];
  const float* bk = (const float*)d_in[7];
  const float* Wv = (const float*)d_in[8];
  const float* bv = (const float*)d_in[9];
  const float* Wo = (const float*)d_in[10];

  char* ws = (char*)d_ws;
  ushort_t* hsb   = (ushort_t*)(ws);               // 16,777,216 B  [4096][2048] bf16
  ushort_t* wtqkv = (ushort_t*)(ws + 16777216);    // 12,582,912 B  [3072][2048] bf16 (Wq|Wk|Wv)^T
  ushort_t* wto   = (ushort_t*)(ws + 29360128);    //  8,388,608 B  [2048][2048] bf16 Wo^T
  ushort_t* qkv   = (ushort_t*)(ws + 37748736);    // 25,165,824 B  [4096][3072] bf16
  ushort_t* vt    = (ushort_t*)(ws + 62914560);    //  4,194,304 B  [8][128][2048] bf16
  float*    linv  = (float*)(ws + 67108864);       //     262,144 B [2][16][2048] f32
  ushort_t* attn  = (ushort_t*)(ws);               // reuse hsb region (dead after gemm_qkv)

  float* outO = (float*)d_out;            // [2,2048,2048] attn_out
  float* outW = outO + (size_t)8388608;   // [2,16,2048,2048] attn_weights

  prep_k<<<8192 + 16384, 256, 0, stream>>>(hs, hsb, Wq, Wk, Wv, Wo, wtqkv, wto);
  gemm_qkv_k<<<768, 256, 0, stream>>>(hsb, wtqkv, qkv, bq, bk, bv, cosT, sinT, vt);
  attn_k<<<512, 256, 0, stream>>>(qkv, vt, linv, attn, outW);
  tail_k<<<1024, 256, 0, stream>>>(attn, wto, outO, qkv, linv, outW);
}

// Round 14
// 299.206 us; speedup vs baseline: 2.5561x; 1.0226x over previous
//
#include <hip/hip_runtime.h>

typedef unsigned short ushort_t;
typedef __attribute__((ext_vector_type(8))) short short8;   // 8 bf16 (4 VGPRs)
typedef __attribute__((ext_vector_type(4))) float f32x4;

#define S_  2048
#define Dm  2048
#define NH  16
#define NKV 4
#define HD_ 128
// SCALE * log2(e): exp(s*SCALE) == exp2(s*C2)
#define C2_ 0.12751879524465536f

__device__ __forceinline__ ushort_t f2bf(float f) {
  union { float f; unsigned u; } v; v.f = f;
  unsigned u = v.u;
  return (ushort_t)((u + 0x7FFFu + ((u >> 16) & 1u)) >> 16);   // RNE
}
__device__ __forceinline__ ushort_t f2bf2(float f) {            // round-half-up (2 VALU ops)
  union { float f; unsigned u; } v; v.f = f;
  return (ushort_t)((v.u + 0x8000u) >> 16);
}
__device__ __forceinline__ float bf2f(ushort_t h) {
  union { unsigned u; float f; } v; v.u = ((unsigned)h) << 16;
  return v.f;
}
__device__ __forceinline__ void gl_lds16(const void* g, void* l) {
  __builtin_amdgcn_global_load_lds((const __attribute__((address_space(1))) void*)g,
                                   (__attribute__((address_space(3))) void*)l, 16, 0, 0);
}

// ---------------- merged prep: bf16 convert (blocks <8192) + 4 weight transposes ----------------
__global__ void prep_k(const float* __restrict__ hs, ushort_t* __restrict__ hsb,
                       const float* __restrict__ Wq, const float* __restrict__ Wk,
                       const float* __restrict__ Wv, const float* __restrict__ Wo,
                       ushort_t* __restrict__ wtqkv, ushort_t* __restrict__ wto) {
  __shared__ float tile[32][33];
  const int id = blockIdx.x;
  if (id < 8192) {
    int i = id * 256 + threadIdx.x;
    float4 v = ((const float4*)hs)[i];
    union { ushort_t u[4]; uint2 v2; } o;
    o.u[0] = f2bf(v.x); o.u[1] = f2bf(v.y); o.u[2] = f2bf(v.z); o.u[3] = f2bf(v.w);
    *(uint2*)&hsb[(size_t)i * 4] = o.v2;
    return;
  }
  const int id2 = id - 8192;
  const int z = id2 >> 12, ky = (id2 >> 6) & 63, nx = id2 & 63;
  const float* src;
  ushort_t* dst;
  int N;
  switch (z) {
    case 0: src = Wq; dst = wtqkv; N = 2048; break;
    case 1: src = Wk; dst = wtqkv + (size_t)2048 * 2048; N = 512; break;
    case 2: src = Wv; dst = wtqkv + (size_t)2560 * 2048; N = 512; break;
    default: src = Wo; dst = wto; N = 2048; break;
  }
  int n0 = nx * 32, k0 = ky * 32;
  if (n0 >= N) return;
  int c = threadIdx.x & 31, r = threadIdx.x >> 5;   // r: 0..7
#pragma unroll
  for (int i = 0; i < 32; i += 8)
    tile[r + i][c] = src[(size_t)(k0 + r + i) * N + n0 + c];
  __syncthreads();
#pragma unroll
  for (int i = 0; i < 32; i += 8)
    dst[(size_t)(n0 + r + i) * 2048 + k0 + c] = f2bf(tile[c][r + i]);
}

// ---------------- GEMM QKV (dbuf, XCD swizzle) + bias + fused RoPE + fused V-transpose ----------
__global__ __launch_bounds__(256, 2) void gemm_qkv_k(
    const ushort_t* __restrict__ A, const ushort_t* __restrict__ Bt, ushort_t* __restrict__ C,
    const float* __restrict__ bq, const float* __restrict__ bk2, const float* __restrict__ bv,
    const float* __restrict__ cosT, const float* __restrict__ sinT, ushort_t* __restrict__ vt) {
  const int N = 3072, K = 2048;
  __shared__ ushort_t smem[16384];   // 32 KB: staging dbuf; later transpose tile / rope fbuf
  ushort_t* lA0 = smem;              // [2][4096], source-pre-swizzled: slot ^= (row>>1)&3
  ushort_t* lB0 = smem + 8192;
  const int lin = blockIdx.x;                    // 768 blocks
  const int nid = (lin & 7) * 96 + (lin >> 3);   // XCD-chunked swizzle (768%8==0)
  const int n0 = (nid % 24) * 128, m0 = (nid / 24) * 128;
  const int t = threadIdx.x;
  const int w = t >> 6, l = t & 63, lr = l & 15, lg = l >> 4;
  const int wr = w >> 1, wc = w & 1;
  const int srow = t >> 2, ssl = t & 3;

  auto stage = [&](int kt, int bufi) {
    int r0 = srow, r1 = srow + 64;
    gl_lds16(A + (size_t)(m0 + r0) * K + kt + ((ssl ^ ((r0 >> 1) & 3)) << 3),
             &lA0[bufi * 4096 + w * 512]);
    gl_lds16(A + (size_t)(m0 + r1) * K + kt + ((ssl ^ ((r1 >> 1) & 3)) << 3),
             &lA0[bufi * 4096 + 2048 + w * 512]);
    gl_lds16(Bt + (size_t)(n0 + r0) * K + kt + ((ssl ^ ((r0 >> 1) & 3)) << 3),
             &lB0[bufi * 4096 + w * 512]);
    gl_lds16(Bt + (size_t)(n0 + r1) * K + kt + ((ssl ^ ((r1 >> 1) & 3)) << 3),
             &lB0[bufi * 4096 + 2048 + w * 512]);
  };

  f32x4 acc[4][4];
#pragma unroll
  for (int i = 0; i < 4; i++)
#pragma unroll
    for (int j = 0; j < 4; j++) acc[i][j] = (f32x4){0.f, 0.f, 0.f, 0.f};

  stage(0, 0);
  const int nit = K / 32;   // 64
  for (int it = 0; it < nit; it++) {
    const int cur = it & 1;
    if (it + 1 < nit) {
      stage((it + 1) * 32, cur ^ 1);
      asm volatile("s_waitcnt vmcnt(4)" ::: "memory");   // current tile's 4 loads done
    } else {
      asm volatile("s_waitcnt vmcnt(0)" ::: "memory");
    }
    __builtin_amdgcn_s_barrier();
    short8 af[4], bfr[4];
#pragma unroll
    for (int mi = 0; mi < 4; mi++) {
      int row = wr * 64 + mi * 16 + lr;
      af[mi] = *(const short8*)((const char*)(lA0 + cur * 4096) + row * 64 +
                                ((lg ^ ((row >> 1) & 3)) << 4));
    }
#pragma unroll
    for (int ni = 0; ni < 4; ni++) {
      int row = wc * 64 + ni * 16 + lr;
      bfr[ni] = *(const short8*)((const char*)(lB0 + cur * 4096) + row * 64 +
                                 ((lg ^ ((row >> 1) & 3)) << 4));
    }
#pragma unroll
    for (int mi = 0; mi < 4; mi++)
#pragma unroll
      for (int ni = 0; ni < 4; ni++)
        acc[mi][ni] = __builtin_amdgcn_mfma_f32_16x16x32_bf16(af[mi], bfr[ni], acc[mi][ni], 0, 0, 0);
    __builtin_amdgcn_s_barrier();   // all waves done reading buf[cur] before restage
  }

  // epilogue: bias; RoPE (Q/K blocks) via partner-wave LDS exchange; V blocks also fill
  // the LDS transpose tile for the fused vt write.
  const bool isV = (n0 >= 2560);
  float* fbuf = (float*)smem;        // 16 KB, staging done
  const int pw_ = w ^ 1;             // partner wave: same wr, wc^1
#pragma unroll
  for (int mi = 0; mi < 4; mi++) {
    float vv[4][4];
#pragma unroll
    for (int ni = 0; ni < 4; ni++)
#pragma unroll
      for (int r = 0; r < 4; r++) {
        int col = n0 + wc * 64 + ni * 16 + lr;
        float bias = (col < 2048) ? bq[col] : (col < 2560) ? bk2[col - 2048] : bv[col - 2560];
        vv[ni][r] = acc[mi][ni][r] + bias;
      }
    if (!isV) {
      __syncthreads();
#pragma unroll
      for (int ni = 0; ni < 4; ni++)
#pragma unroll
        for (int r = 0; r < 4; r++)
          fbuf[w * 1024 + (lg * 4 + r) * 64 + ni * 16 + lr] = vv[ni][r];
      __syncthreads();
#pragma unroll
      for (int ni = 0; ni < 4; ni++)
#pragma unroll
        for (int r = 0; r < 4; r++) {
          float pv = fbuf[pw_ * 1024 + (lg * 4 + r) * 64 + ni * 16 + lr];
          int row = m0 + wr * 64 + mi * 16 + lg * 4 + r;   // = b*2048+s
          int d = wc * 64 + ni * 16 + lr;                  // 0..127 within head
          float c = cosT[(size_t)row * HD_ + d];
          float sn = sinT[(size_t)row * HD_ + d];
          vv[ni][r] = (wc == 0) ? vv[ni][r] * c - pv * sn : vv[ni][r] * c + pv * sn;
        }
    }
#pragma unroll
    for (int ni = 0; ni < 4; ni++)
#pragma unroll
      for (int r = 0; r < 4; r++) {
        int row = m0 + wr * 64 + mi * 16 + lg * 4 + r;
        int col = n0 + wc * 64 + ni * 16 + lr;
        ushort_t hv = f2bf(vv[ni][r]);
        C[(size_t)row * N + col] = hv;
        if (isV) {
          int colL = wc * 64 + ni * 16 + lr;            // d within head
          int rowL = wr * 64 + mi * 16 + lg * 4 + r;    // s within tile
          smem[colL * 128 + (rowL ^ ((colL & 7) << 4))] = hv;
        }
      }
  }
  if (isV) {
    __syncthreads();
    const int kvh = (n0 - 2560) >> 7;
    const int b = m0 >> 11, s0v = m0 & 2047;
    const size_t vbase = (size_t)(b * 4 + kvh) * 128;
#pragma unroll
    for (int j = 0; j < 8; j++) {
      int cid = j * 256 + t;
      int d = cid >> 4, sc = cid & 15;
      int rowStart = (sc * 8) ^ ((d & 7) << 4);
      short8 v8 = *(const short8*)&smem[d * 128 + rowStart];
      *(short8*)&vt[(vbase + d) * S_ + s0v + sc * 8] = v8;
    }
  }
}

// ---------------- fused causal GQA attention + attn_weights, single pass + norm sweep ---------
// 512 blocks (XCD-chunk swizzled; each XCD chunk shares one (b,kvh) K/V panel -> L2-hot).
// Block handles q-tiles {pi, 31-pi}: constant 33 k-tiles. Per q-tile:
//  sweep 1: QK^T + exp2 + PV accumulate (dbuf K+V), row-sum -> inv_l in registers
//  epilogue: normalized attnO (bf16) + zero-fill of outW upper triangle
//  sweep 2: QK^T recompute (dbuf K only, L2-hot) -> outW = exp2 * inv_l (fp32, causal region)
__global__ __launch_bounds__(256, 2) void attn_k(
    const ushort_t* __restrict__ qkv, const ushort_t* __restrict__ vt,
    ushort_t* __restrict__ attnO, float* __restrict__ outW) {
  __shared__ ushort_t lK[2][64 * 128];   // [k][d], 16 slots/row, slot ^= row&15
  __shared__ ushort_t lV[2][128 * 64];   // [d][k], 8 slots/row,  slot ^= row&7
  __shared__ ushort_t lP[4][16 * 64];    // per-wave P~ (16 rows), slot ^= row&7
  const int nid = (blockIdx.x & 7) * 64 + (blockIdx.x >> 3);   // 512%8==0, bijective
  const int pairI = nid & 15, h = (nid >> 4) & 15, b = nid >> 8;
  const int kvh = h >> 2;
  const int t = threadIdx.x, w = t >> 6, l = t & 63, lr = l & 15, lg = l >> 4;
  ushort_t* lPw = lP[w];

  auto stageKV = [&](int kt, int bufi) {
#pragma unroll
    for (int c = 0; c < 4; c++) {
      int row = c * 16 + (t >> 4), sl = t & 15;
      gl_lds16(qkv + (size_t)(b * S_ + kt * 64 + row) * 3072 + 2048 + kvh * HD_ +
                   ((sl ^ (row & 15)) << 3),
               &lK[bufi][c * 2048 + w * 512]);
    }
#pragma unroll
    for (int c = 0; c < 4; c++) {
      int row = c * 32 + (t >> 3), sl = t & 7;
      gl_lds16(vt + (size_t)((b * 4 + kvh) * 128 + row) * S_ + kt * 64 +
                   ((sl ^ (row & 7)) << 3),
               &lV[bufi][c * 2048 + w * 512]);
    }
  };
  auto stageK = [&](int kt, int bufi) {
#pragma unroll
    for (int c = 0; c < 4; c++) {
      int row = c * 16 + (t >> 4), sl = t & 15;
      gl_lds16(qkv + (size_t)(b * S_ + kt * 64 + row) * 3072 + 2048 + kvh * HD_ +
                   ((sl ^ (row & 15)) << 3),
               &lK[bufi][c * 2048 + w * 512]);
    }
  };

  for (int sel = 0; sel < 2; sel++) {
    const int qt = sel ? (31 - pairI) : pairI;   // 64-row q-tile index, 0..31
    const int qw = qt * 64 + w * 16;             // this wave's 16 q-rows
    const int nkt = qt + 1;                      // 64-wide k-tiles in causal range

    // Q fragments (A-frag: row=lane&15, k=(lane>>4)*8+i)
    short8 qf[4];
#pragma unroll
    for (int kc = 0; kc < 4; kc++)
      qf[kc] = *(const short8*)&qkv[(size_t)(b * S_ + qw + lr) * 3072 + h * HD_ + kc * 32 + lg * 8];

    float lsum[4];
    f32x4 o[8];
#pragma unroll
    for (int r = 0; r < 4; r++) lsum[r] = 0.f;
#pragma unroll
    for (int dj = 0; dj < 8; dj++) o[dj] = (f32x4){0.f, 0.f, 0.f, 0.f};

    // ======== sweep 1: attention accumulate ========
    stageKV(0, 0);
    for (int kt = 0; kt < nkt; kt++) {
      const int cur = kt & 1;
      if (kt + 1 < nkt) {
        stageKV(kt + 1, cur ^ 1);
        asm volatile("s_waitcnt vmcnt(8)" ::: "memory");   // current tile's 8 loads done
      } else {
        asm volatile("s_waitcnt vmcnt(0)" ::: "memory");
      }
      __builtin_amdgcn_s_barrier();

      // S = Q K^T
      f32x4 s[4];
#pragma unroll
      for (int ni = 0; ni < 4; ni++) s[ni] = (f32x4){0.f, 0.f, 0.f, 0.f};
      __builtin_amdgcn_s_setprio(1);
#pragma unroll
      for (int kc = 0; kc < 4; kc++) {
        short8 kf[4];
#pragma unroll
        for (int ni = 0; ni < 4; ni++) {
          int row = ni * 16 + lr;
          kf[ni] = *(const short8*)((const char*)lK[cur] + row * 256 +
                                    (((kc * 4 + lg) ^ (row & 15)) << 4));
        }
#pragma unroll
        for (int ni = 0; ni < 4; ni++)
          s[ni] = __builtin_amdgcn_mfma_f32_16x16x32_bf16(qf[kc], kf[ni], s[ni], 0, 0, 0);
      }
      __builtin_amdgcn_s_setprio(0);

      // P~ = exp2(S*C2); mask only on the diagonal tile (separate clean path otherwise)
      if (kt == nkt - 1) {
#pragma unroll
        for (int ni = 0; ni < 4; ni++)
#pragma unroll
          for (int r = 0; r < 4; r++) {
            float p = exp2f(s[ni][r] * C2_);
            int colg = kt * 64 + ni * 16 + lr;
            int rowg = qw + lg * 4 + r;
            if (colg > rowg) p = 0.f;
            lsum[r] += p;
            int rowl = lg * 4 + r, col = ni * 16 + lr;
            lPw[rowl * 64 + (((col >> 3) ^ (rowl & 7)) << 3) + (col & 7)] = f2bf2(p);
          }
      } else {
#pragma unroll
        for (int ni = 0; ni < 4; ni++)
#pragma unroll
          for (int r = 0; r < 4; r++) {
            float p = exp2f(s[ni][r] * C2_);
            lsum[r] += p;
            int rowl = lg * 4 + r, col = ni * 16 + lr;
            lPw[rowl * 64 + (((col >> 3) ^ (rowl & 7)) << 3) + (col & 7)] = f2bf2(p);
          }
      }

      // O += P~ V
      __builtin_amdgcn_s_setprio(1);
#pragma unroll
      for (int kc = 0; kc < 2; kc++) {
        short8 pa;
        {
          int row = lr;
          pa = *(const short8*)((const char*)lPw + row * 128 + (((kc * 4 + lg) ^ (row & 7)) << 4));
        }
#pragma unroll
        for (int dj = 0; dj < 8; dj++) {
          int row = dj * 16 + lr;
          short8 vb = *(const short8*)((const char*)lV[cur] + row * 128 +
                                       (((kc * 4 + lg) ^ (row & 7)) << 4));
          o[dj] = __builtin_amdgcn_mfma_f32_16x16x32_bf16(pa, vb, o[dj], 0, 0, 0);
        }
      }
      __builtin_amdgcn_s_setprio(0);
      __builtin_amdgcn_s_barrier();   // all waves done reading buf[cur] before restage
    }

    // row-sum reduce over the 16 lr lanes -> inv_l (registers only)
    float inv_l[4];
#pragma unroll
    for (int r = 0; r < 4; r++) {
      float sum = lsum[r];
#pragma unroll
      for (int off = 1; off < 16; off <<= 1) sum += __shfl_xor(sum, off);
      inv_l[r] = 1.f / sum;
    }
    // normalized O -> attn buffer (bf16)
#pragma unroll
    for (int dj = 0; dj < 8; dj++)
#pragma unroll
      for (int r = 0; r < 4; r++) {
        int rowg = b * S_ + qw + lg * 4 + r;
        int colg = h * HD_ + dj * 16 + lr;
        attnO[(size_t)rowg * Dm + colg] = f2bf(o[dj][r] * inv_l[r]);
      }

    // zero-fill outW strict upper triangle for this wave's 16 rows (cols >= nkt*64).
    {
      const int zc0 = nkt * 64;
      const int zn = (S_ - zc0) >> 2;   // float4 per row (multiple of 16, may be 0)
      f32x4 z = {0.f, 0.f, 0.f, 0.f};
      const int bh = b * NH + h;
      for (int rr = 0; rr < 16; rr++) {
        f32x4* base = (f32x4*)&outW[((size_t)bh * S_ + qw + rr) * S_ + zc0];
        for (int cc = l; cc < zn; cc += 64) __builtin_nontemporal_store(z, base + cc);
      }
    }

    // ======== sweep 2: recompute QK^T (K only, L2-hot), write normalized fp32 outW ========
    {
      const int bh = b * NH + h;
      stageK(0, 0);
      for (int kt = 0; kt < nkt; kt++) {
        const int cur = kt & 1;
        if (kt + 1 < nkt) {
          stageK(kt + 1, cur ^ 1);
          asm volatile("s_waitcnt vmcnt(4)" ::: "memory");
        } else {
          asm volatile("s_waitcnt vmcnt(0)" ::: "memory");
        }
        __builtin_amdgcn_s_barrier();

        f32x4 s[4];
#pragma unroll
        for (int ni = 0; ni < 4; ni++) s[ni] = (f32x4){0.f, 0.f, 0.f, 0.f};
        __builtin_amdgcn_s_setprio(1);
#pragma unroll
        for (int kc = 0; kc < 4; kc++) {
          short8 kf[4];
#pragma unroll
          for (int ni = 0; ni < 4; ni++) {
            int row = ni * 16 + lr;
            kf[ni] = *(const short8*)((const char*)lK[cur] + row * 256 +
                                      (((kc * 4 + lg) ^ (row & 15)) << 4));
          }
#pragma unroll
          for (int ni = 0; ni < 4; ni++)
            s[ni] = __builtin_amdgcn_mfma_f32_16x16x32_bf16(qf[kc], kf[ni], s[ni], 0, 0, 0);
        }
        __builtin_amdgcn_s_setprio(0);

        const bool diag = (kt == nkt - 1);
#pragma unroll
        for (int ni = 0; ni < 4; ni++)
#pragma unroll
          for (int r = 0; r < 4; r++) {
            int colg = kt * 64 + ni * 16 + lr;
            int rowg = qw + lg * 4 + r;
            float p = exp2f(s[ni][r] * C2_) * inv_l[r];
            if (diag && colg > rowg) p = 0.f;
            outW[((size_t)bh * S_ + rowg) * S_ + colg] = p;
          }
        __builtin_amdgcn_s_barrier();   // all waves done reading lK[cur] before restage
      }
    }
  }
}

// ---------------- tail: pure Wo projection GEMM (dbuf, XCD swizzle), full machine -------------
__global__ __launch_bounds__(256, 2) void tail_k(
    const ushort_t* __restrict__ A, const ushort_t* __restrict__ Bt, float* __restrict__ outO) {
  __shared__ ushort_t sh[2][64 * 128];   // 32 KB
  const int t = threadIdx.x;
  const int w = t >> 6, l = t & 63, lr = l & 15, lg = l >> 4;
  const int N = 2048, K = 2048;
  const int nid = (blockIdx.x & 7) * 64 + (blockIdx.x >> 3);   // XCD-chunked, 512%8==0
  const int n0 = (nid & 15) * 128, m0 = (nid >> 4) * 128;
  const int wr = w >> 1, wc = w & 1;
  const int srow = t >> 2, ssl = t & 3;

  auto stageG = [&](int kt, int bufi) {
    int r0 = srow, r1 = srow + 64;
    gl_lds16(A + (size_t)(m0 + r0) * K + kt + ((ssl ^ ((r0 >> 1) & 3)) << 3), &sh[bufi][w * 512]);
    gl_lds16(A + (size_t)(m0 + r1) * K + kt + ((ssl ^ ((r1 >> 1) & 3)) << 3),
             &sh[bufi][2048 + w * 512]);
    gl_lds16(Bt + (size_t)(n0 + r0) * K + kt + ((ssl ^ ((r0 >> 1) & 3)) << 3),
             &sh[bufi][4096 + w * 512]);
    gl_lds16(Bt + (size_t)(n0 + r1) * K + kt + ((ssl ^ ((r1 >> 1) & 3)) << 3),
             &sh[bufi][4096 + 2048 + w * 512]);
  };

  f32x4 acc[4][4];
#pragma unroll
  for (int i = 0; i < 4; i++)
#pragma unroll
    for (int j = 0; j < 4; j++) acc[i][j] = (f32x4){0.f, 0.f, 0.f, 0.f};

  stageG(0, 0);
  const int nit = K / 32;
  for (int it = 0; it < nit; it++) {
    const int cur = it & 1;
    if (it + 1 < nit) {
      stageG((it + 1) * 32, cur ^ 1);
      asm volatile("s_waitcnt vmcnt(4)" ::: "memory");
    } else {
      asm volatile("s_waitcnt vmcnt(0)" ::: "memory");
    }
    __builtin_amdgcn_s_barrier();
    short8 af[4], bfr[4];
#pragma unroll
    for (int mi = 0; mi < 4; mi++) {
      int row = wr * 64 + mi * 16 + lr;
      af[mi] =
          *(const short8*)((const char*)&sh[cur][0] + row * 64 + ((lg ^ ((row >> 1) & 3)) << 4));
    }
#pragma unroll
    for (int ni = 0; ni < 4; ni++) {
      int row = wc * 64 + ni * 16 + lr;
      bfr[ni] = *(const short8*)((const char*)&sh[cur][4096] + row * 64 +
                                 ((lg ^ ((row >> 1) & 3)) << 4));
    }
#pragma unroll
    for (int mi = 0; mi < 4; mi++)
#pragma unroll
      for (int ni = 0; ni < 4; ni++)
        acc[mi][ni] =
            __builtin_amdgcn_mfma_f32_16x16x32_bf16(af[mi], bfr[ni], acc[mi][ni], 0, 0, 0);
    __builtin_amdgcn_s_barrier();
  }
#pragma unroll
  for (int mi = 0; mi < 4; mi++)
#pragma unroll
    for (int ni = 0; ni < 4; ni++)
#pragma unroll
      for (int r = 0; r < 4; r++) {
        int row = m0 + wr * 64 + mi * 16 + lg * 4 + r;
        int col = n0 + wc * 64 + ni * 16 + lr;
        outO[(size_t)row * N + col] = acc[mi][ni][r];
      }
}

// ---------------- host ----------------
extern "C" void kernel_launch(void* const* d_in, const int* in_sizes, int n_in,
                              void* d_out, int out_size, void* d_ws, size_t ws_size,
                              hipStream_t stream) {
  const float* hs   = (const float*)d_in[0];
  const float* cosT = (const float*)d_in[1];
  const float* sinT = (const float*)d_in[2];
  // d_in[3] attention_mask: pure causal, applied analytically
  const float* Wq = (const float*)d_in[4];
  const float* bq = (const float*)d_in[5];
  const float* Wk = (const float*)d_in[6];
  const float* bk = (const float*)d_in[7];
  const float* Wv = (const float*)d_in[8];
  const float* bv = (const float*)d_in[9];
  const float* Wo = (const float*)d_in[10];

  char* ws = (char*)d_ws;
  ushort_t* hsb   = (ushort_t*)(ws);               // 16,777,216 B  [4096][2048] bf16
  ushort_t* wtqkv = (ushort_t*)(ws + 16777216);    // 12,582,912 B  [3072][2048] bf16 (Wq|Wk|Wv)^T
  ushort_t* wto   = (ushort_t*)(ws + 29360128);    //  8,388,608 B  [2048][2048] bf16 Wo^T
  ushort_t* qkv   = (ushort_t*)(ws + 37748736);    // 25,165,824 B  [4096][3072] bf16
  ushort_t* vt    = (ushort_t*)(ws + 62914560);    //  4,194,304 B  [8][128][2048] bf16
  ushort_t* attn  = (ushort_t*)(ws);               // reuse hsb region (dead after gemm_qkv)

  float* outO = (float*)d_out;            // [2,2048,2048] attn_out
  float* outW = outO + (size_t)8388608;   // [2,16,2048,2048] attn_weights

  prep_k<<<8192 + 16384, 256, 0, stream>>>(hs, hsb, Wq, Wk, Wv, Wo, wtqkv, wto);
  gemm_qkv_k<<<768, 256, 0, stream>>>(hsb, wtqkv, qkv, bq, bk, bv, cosT, sinT, vt);
  attn_k<<<512, 256, 0, stream>>>(qkv, vt, attn, outW);
  tail_k<<<512, 256, 0, stream>>>(attn, wto, outO);
}